// Round 4
// baseline (1107.422 us; speedup 1.0000x reference)
//
#include <hip/hip_runtime.h>

#define EPS 1e-5f
#define NRED 65536.0f   // B*H*W = 64*32*32
#define IMST 73984      // 34*34*64 halo image stride (elements)

typedef short bf16x8 __attribute__((ext_vector_type(8)));
typedef float f32x4 __attribute__((ext_vector_type(4)));
typedef unsigned short u16;

__device__ __forceinline__ u16 f2bf(float x) {  // RNE f32->bf16
  union { float f; unsigned u; } v; v.f = x;
  unsigned r = v.u + 0x7FFF + ((v.u >> 16) & 1);
  return (u16)(r >> 16);
}
__device__ __forceinline__ float bf2f(u16 h) {
  union { unsigned u; float f; } v; v.u = ((unsigned)h) << 16;
  return v.f;
}
__device__ __forceinline__ unsigned pk2(float a, float b) {
  return (unsigned)f2bf(a) | ((unsigned)f2bf(b) << 16);
}

// st layout (floats): [0,64) s1 | [64,128) b1 | [128,640) sum2[k][c] |
// [640,1152) sumsq2[k][c] | [1792,1856) bias2[c] | [8192,8256) cm[c]

__global__ void prep_cm_k(const float* __restrict__ a1, const float* __restrict__ a2,
                          float* __restrict__ st) {
  int c = threadIdx.x, g = c >> 3;
  float m1 = 0.f, m2 = 0.f;
  for (int i = g; i < 8; ++i) { m1 += a1[i]; m2 += a2[i]; }
  st[8192 + c] = m1 * m2;
}

// wT1[e][tap][co][ci] bf16
__global__ void pack_wT1_k(const float* __restrict__ w0, const float* __restrict__ w1,
                           const float* __restrict__ w2, const float* __restrict__ w3,
                           u16* __restrict__ wT1) {
  int e = blockIdx.x / 9, tap = blockIdx.x % 9;
  const float* w = e == 0 ? w0 : e == 1 ? w1 : e == 2 ? w2 : w3;
  u16* dst = wT1 + e * 36864 + tap * 4096;
  for (int idx = threadIdx.x; idx < 4096; idx += 256) {
    int co = idx >> 6, ci = idx & 63;
    dst[idx] = f2bf(w[(co * 64 + ci) * 9 + tap]);
  }
}

// wG[e][g*12+ch*4+q][co][cig] bf16, zero where tap=ch*4+q > 8
__global__ void pack_wG_k(const float* __restrict__ w0, const float* __restrict__ w1,
                          const float* __restrict__ w2, const float* __restrict__ w3,
                          u16* __restrict__ wG) {
  int e = blockIdx.y;
  const float* w = e == 0 ? w0 : e == 1 ? w1 : e == 2 ? w2 : w3;
  int bx = blockIdx.x;              // g*12 + ch*4 + q
  int q = bx & 3, ch = (bx >> 2) % 3, g = bx / 12;
  int tap = ch * 4 + q;
  u16* dst = wG + e * 49152 + bx * 512;
  for (int idx = threadIdx.x; idx < 512; idx += 256) {
    int co = idx >> 3, cig = idx & 7;
    float v = (tap <= 8) ? w[(co * 64 + g * 8 + cig) * 9 + tap] : 0.f;
    dst[idx] = f2bf(v);
  }
}

// x (NCHW f32) -> xT = bf16(relu(x)) halo pixel-major. grid 1024 (b*16+slab), block 256.
__global__ __launch_bounds__(256) void transpose_k(const float* __restrict__ x,
                                                   u16* __restrict__ xT) {
  __shared__ __align__(16) u16 sh[64 * 72];
  const int tid = threadIdx.x;
  const int b = blockIdx.x >> 4, slab = blockIdx.x & 15;
  const int ln = tid & 63, w = tid >> 6;
  const float* xb = x + (size_t)b * 65536 + slab * 64;
#pragma unroll
  for (int i = 0; i < 16; ++i) {
    int ci = w + i * 4;
    float v = xb[ci * 1024 + ln];
    sh[ln * 72 + ci] = f2bf(fmaxf(v, 0.f));
  }
  __syncthreads();
  u16* dst = xT + (size_t)b * IMST;
#pragma unroll
  for (int j = 0; j < 2; ++j) {
    int idx = tid + j * 256;
    int p = idx >> 3, oct = idx & 7;
    int gp = slab * 64 + p;
    int R = gp >> 5, C = gp & 31;
    *(uint4*)&dst[((R + 1) * 34 + C + 1) * 64 + oct * 8] = *(const uint4*)&sh[p * 72 + oct * 8];
  }
}

// ---------------- convA: t = conv3x3(xin, W1) + per-block stats partials -----
// block 256 = 4 waves (tr = w>>1, colhalf = w&1); grid (16 rowpairs, 64 b)
__global__ __launch_bounds__(256) void convA_k(const u16* __restrict__ xin,
                                               const u16* __restrict__ wT,
                                               u16* __restrict__ t,
                                               float* __restrict__ pA) {
  __shared__ float sA[64], qA[64];
  const int tid = threadIdx.x;
  const int b = blockIdx.y;
  if (tid < 64) { sA[tid] = 0.f; qA[tid] = 0.f; }
  __syncthreads();
  const int lane = tid & 63, w = tid >> 6;
  const int ln = lane & 15, quad = lane >> 4;
  const int R = blockIdx.x * 2 + (w >> 1);
  const int C = (w & 1) * 16 + ln;
  const size_t baseB = (size_t)b * IMST + (size_t)(R * 34 + C) * 64 + quad * 8;
  f32x4 acc[4];
#pragma unroll
  for (int mt = 0; mt < 4; ++mt) acc[mt] = (f32x4){0.f, 0.f, 0.f, 0.f};
#pragma unroll 1
  for (int tap = 0; tap < 9; ++tap) {
    const size_t po = baseB + (size_t)((tap / 3) * 34 + tap % 3) * 64;
#pragma unroll
    for (int half = 0; half < 2; ++half) {
      bf16x8 bx = *(const bf16x8*)&xin[po + half * 32];
#pragma unroll
      for (int mt = 0; mt < 4; ++mt) {
        bf16x8 aw = *(const bf16x8*)&wT[(tap * 64 + mt * 16 + ln) * 64 + half * 32 + quad * 8];
        acc[mt] = __builtin_amdgcn_mfma_f32_16x16x32_bf16(aw, bx, acc[mt], 0, 0, 0);
      }
    }
  }
  u16* tb = t + (size_t)b * IMST + (size_t)((R + 1) * 34 + C + 1) * 64;
#pragma unroll
  for (int mt = 0; mt < 4; ++mt) {
    uint2 pk;
    pk.x = pk2(acc[mt][0], acc[mt][1]);
    pk.y = pk2(acc[mt][2], acc[mt][3]);
    *(uint2*)&tb[mt * 16 + quad * 4] = pk;
#pragma unroll
    for (int r = 0; r < 4; ++r) {
      float v = acc[mt][r];
      float s = v, q = v * v;
      s += __shfl_xor(s, 1); q += __shfl_xor(q, 1);
      s += __shfl_xor(s, 2); q += __shfl_xor(q, 2);
      s += __shfl_xor(s, 4); q += __shfl_xor(q, 4);
      s += __shfl_xor(s, 8); q += __shfl_xor(q, 8);
      if (ln == 0) {
        atomicAdd(&sA[mt * 16 + quad * 4 + r], s);
        atomicAdd(&qA[mt * 16 + quad * 4 + r], q);
      }
    }
  }
  __syncthreads();
  const int blk = blockIdx.y * 16 + blockIdx.x;
  if (tid < 64) pA[blk * 128 + tid] = sA[tid];
  else if (tid < 128) pA[blk * 128 + tid] = qA[tid - 64];
}

// reducerA: sum partials -> s1/b1 in st. 1 block, 128 thr.
__global__ void reducerA_k(const float* __restrict__ pA, const float* __restrict__ a1,
                           float* __restrict__ st) {
  __shared__ float red[128];
  int tid = threadIdx.x;
  float s = 0.f;
  for (int b2 = 0; b2 < 1024; ++b2) s += pA[b2 * 128 + tid];
  red[tid] = s;
  __syncthreads();
  if (tid < 64) {
    int g = tid >> 3;
    float m = 0.f;
    for (int i = g; i < 8; ++i) m += a1[i];
    float mu = red[tid] * (1.f / NRED);
    float var = red[64 + tid] * (1.f / NRED) - mu * mu;
    float r = rsqrtf(var + EPS);
    st[tid] = r * m;
    st[64 + tid] = -mu * r * m;
  }
}

// renorm: t := bf16(t*s1[ci] + b1[ci]) interior only. grid 2048, block 256.
__global__ __launch_bounds__(256) void renorm_k(u16* __restrict__ t,
                                                const float* __restrict__ st) {
  __shared__ float s1L[64], b1L[64];
  int tid = threadIdx.x;
  if (tid < 64) { s1L[tid] = st[tid]; b1L[tid] = st[64 + tid]; }
  __syncthreads();
  int idx = blockIdx.x * 256 + tid;
  int b = idx >> 13, rem = idx & 8191;
  int p = rem >> 3, oct = rem & 7;
  int R = p >> 5, C = p & 31;
  u16* ptr = t + (size_t)b * IMST + (size_t)((R + 1) * 34 + C + 1) * 64 + oct * 8;
  uint4 u = *(const uint4*)ptr;
  unsigned vals[4] = {u.x, u.y, u.z, u.w};
  uint4 o;
  unsigned res[4];
#pragma unroll
  for (int i = 0; i < 4; ++i) {
    int ci = oct * 8 + i * 2;
    float lo = bf2f((u16)(vals[i] & 0xffff)) * s1L[ci] + b1L[ci];
    float hi = bf2f((u16)(vals[i] >> 16)) * s1L[ci + 1] + b1L[ci + 1];
    res[i] = pk2(lo, hi);
  }
  o.x = res[0]; o.y = res[1]; o.z = res[2]; o.w = res[3];
  *(uint4*)ptr = o;
}

// ---------------- convC: per-group prefix stats of conv2 ---------------------
// block 512 = 8 waves (nt = w&3 pxtile, ch2 = w>>2 co-half); grid (16, 64)
__global__ __launch_bounds__(512) void convC_k(const u16* __restrict__ t,
                                               const u16* __restrict__ wG,
                                               float* __restrict__ pC) {
  __shared__ float sC[512], qC[512];
  const int tid = threadIdx.x;
  const int b = blockIdx.y;
  sC[tid] = 0.f; qC[tid] = 0.f;
  __syncthreads();
  const int lane = tid & 63, w = tid >> 6;
  const int ln = lane & 15, quad = lane >> 4;
  const int nt = w & 3, ch2 = w >> 2;
  const int R = blockIdx.x * 2 + (nt >> 1);
  const int C = (nt & 1) * 16 + ln;
  const size_t baseB = (size_t)b * IMST + (size_t)(R * 34 + C) * 64;
  size_t po[3];
#pragma unroll
  for (int ch = 0; ch < 3; ++ch) {
    int tp = ch * 4 + quad; if (tp > 8) tp = 8;  // A is zero there
    po[ch] = baseB + (size_t)((tp / 3) * 34 + tp % 3) * 64;
  }
  f32x4 acc[8][2];
#pragma unroll
  for (int g = 0; g < 8; ++g)
#pragma unroll
    for (int m = 0; m < 2; ++m) acc[g][m] = (f32x4){0.f, 0.f, 0.f, 0.f};
#pragma unroll
  for (int g = 0; g < 8; ++g) {
#pragma unroll
    for (int ch = 0; ch < 3; ++ch) {
      bf16x8 bx = *(const bf16x8*)&t[po[ch] + g * 8];
#pragma unroll
      for (int mtl = 0; mtl < 2; ++mtl) {
        bf16x8 aw = *(const bf16x8*)&wG[((g * 12 + ch * 4 + quad) * 64 + ch2 * 32 + mtl * 16 + ln) * 8];
        acc[g][mtl] = __builtin_amdgcn_mfma_f32_16x16x32_bf16(aw, bx, acc[g][mtl], 0, 0, 0);
      }
    }
  }
  f32x4 P[2];
  P[0] = (f32x4){0.f, 0.f, 0.f, 0.f};
  P[1] = (f32x4){0.f, 0.f, 0.f, 0.f};
#pragma unroll
  for (int k = 0; k < 8; ++k) {
    P[0] += acc[k][0]; P[1] += acc[k][1];
#pragma unroll
    for (int mtl = 0; mtl < 2; ++mtl) {
#pragma unroll
      for (int r = 0; r < 4; ++r) {
        float s = P[mtl][r], q = s * s;
        s += __shfl_xor(s, 1); q += __shfl_xor(q, 1);
        s += __shfl_xor(s, 2); q += __shfl_xor(q, 2);
        s += __shfl_xor(s, 4); q += __shfl_xor(q, 4);
        s += __shfl_xor(s, 8); q += __shfl_xor(q, 8);
        if (ln == 0) {
          int co = ch2 * 32 + mtl * 16 + quad * 4 + r;
          atomicAdd(&sC[k * 64 + co], s);
          atomicAdd(&qC[k * 64 + co], q);
        }
      }
    }
  }
  __syncthreads();
  const int blk = blockIdx.y * 16 + blockIdx.x;
  pC[blk * 1024 + tid] = sC[tid];
  pC[blk * 1024 + 512 + tid] = qC[tid];
}

// reducerC: 1 block, 1024 thr -> st[128..1152)
__global__ void reducerC_k(const float* __restrict__ pC, float* __restrict__ st) {
  int tid = threadIdx.x;
  float s = 0.f;
  for (int b2 = 0; b2 < 1024; ++b2) s += pC[b2 * 1024 + tid];
  if (tid < 512) st[128 + tid] = s;
  else st[640 + (tid - 512)] = s;
}

// prepE: finalizeC + fold g into conv2 weights. grid 9, block 256.
__global__ void prepE_k(const float* __restrict__ w2, float* __restrict__ st,
                        const float* __restrict__ a2, u16* __restrict__ wE) {
  __shared__ float gL[512];
  int tid = threadIdx.x, tap = blockIdx.x;
  if (tid < 64) {
    int c = tid;
    float suf = 0.f, bias = 0.f;
    for (int k = 7; k >= 0; --k) {
      float mu = st[128 + k * 64 + c] * (1.f / NRED);
      float var = st[640 + k * 64 + c] * (1.f / NRED) - mu * mu;
      float rr = rsqrtf(var + EPS);
      bias -= a2[k] * mu * rr;
      suf += a2[k] * rr;
      gL[k * 64 + c] = suf;
    }
    st[1792 + c] = bias;
  }
  __syncthreads();
  for (int idx = tid; idx < 4096; idx += 256) {
    int co = idx >> 6, ci = idx & 63;
    wE[tap * 4096 + idx] = f2bf(w2[(co * 64 + ci) * 9 + tap] * gL[(ci >> 3) * 64 + co]);
  }
}

// ---------------- convE: mixed conv2 + fused epilogue ------------------------
// block 256 = 4 waves; grid (16, 64)
// MODE 0: n1T/n1reluT | 1: n2reluT = relu(v + pool(n1T)*cm) | 2: out = v + x*cm | 3: out += v
template <int MODE>
__global__ __launch_bounds__(256) void convE_k(const u16* __restrict__ t,
                                               const float* __restrict__ st,
                                               const u16* __restrict__ wE,
                                               float* __restrict__ outp,
                                               const float* __restrict__ xin,
                                               u16* __restrict__ d1,
                                               u16* __restrict__ d2) {
  __shared__ float cmL[64], biasL[64];
  const int tid = threadIdx.x;
  const int b = blockIdx.y;
  if (tid < 64) { cmL[tid] = st[8192 + tid]; biasL[tid] = st[1792 + tid]; }
  __syncthreads();
  const int lane = tid & 63, w = tid >> 6;
  const int ln = lane & 15, quad = lane >> 4;
  const int R = blockIdx.x * 2 + (w >> 1);
  const int C = (w & 1) * 16 + ln;
  const size_t baseB = (size_t)b * IMST + (size_t)(R * 34 + C) * 64 + quad * 8;
  f32x4 acc[4];
#pragma unroll
  for (int mt = 0; mt < 4; ++mt) acc[mt] = (f32x4){0.f, 0.f, 0.f, 0.f};
#pragma unroll 1
  for (int tap = 0; tap < 9; ++tap) {
    const size_t po = baseB + (size_t)((tap / 3) * 34 + tap % 3) * 64;
#pragma unroll
    for (int half = 0; half < 2; ++half) {
      bf16x8 bx = *(const bf16x8*)&t[po + half * 32];
#pragma unroll
      for (int mt = 0; mt < 4; ++mt) {
        bf16x8 aw = *(const bf16x8*)&wE[(tap * 64 + mt * 16 + ln) * 64 + half * 32 + quad * 8];
        acc[mt] = __builtin_amdgcn_mfma_f32_16x16x32_bf16(aw, bx, acc[mt], 0, 0, 0);
      }
    }
  }
  const size_t haloPx = (size_t)b * IMST + (size_t)((R + 1) * 34 + C + 1) * 64;
#pragma unroll
  for (int mt = 0; mt < 4; ++mt) {
    int cob = mt * 16 + quad * 4;
    float v[4];
#pragma unroll
    for (int r = 0; r < 4; ++r) v[r] = acc[mt][r] + biasL[cob + r];
    if (MODE == 0) {
      uint2 pk, pkr;
      pk.x = pk2(v[0], v[1]); pk.y = pk2(v[2], v[3]);
      pkr.x = pk2(fmaxf(v[0], 0.f), fmaxf(v[1], 0.f));
      pkr.y = pk2(fmaxf(v[2], 0.f), fmaxf(v[3], 0.f));
      *(uint2*)&d1[haloPx + cob] = pk;    // n1T (raw, for pool)
      *(uint2*)&d2[haloPx + cob] = pkr;   // n1reluT (for e2 convA)
    } else if (MODE == 1) {
      float ps[4] = {0.f, 0.f, 0.f, 0.f};
      const size_t pb = (size_t)b * IMST + (size_t)(R * 34 + C) * 64 + cob;
#pragma unroll
      for (int dy = 0; dy < 3; ++dy)
#pragma unroll
        for (int dx = 0; dx < 3; ++dx) {
          uint2 u = *(const uint2*)&d2[pb + (size_t)(dy * 34 + dx) * 64];  // d2 = n1T
          ps[0] += bf2f((u16)(u.x & 0xffff));
          ps[1] += bf2f((u16)(u.x >> 16));
          ps[2] += bf2f((u16)(u.y & 0xffff));
          ps[3] += bf2f((u16)(u.y >> 16));
        }
      float rows = 3.f - (R == 0 ? 1.f : 0.f) - (R == 31 ? 1.f : 0.f);
      float cols = 3.f - (C == 0 ? 1.f : 0.f) - (C == 31 ? 1.f : 0.f);
      float inv = 1.f / (rows * cols);
      uint2 pkr;
      float t0 = fmaxf(v[0] + ps[0] * inv * cmL[cob], 0.f);
      float t1 = fmaxf(v[1] + ps[1] * inv * cmL[cob + 1], 0.f);
      float t2 = fmaxf(v[2] + ps[2] * inv * cmL[cob + 2], 0.f);
      float t3 = fmaxf(v[3] + ps[3] * inv * cmL[cob + 3], 0.f);
      pkr.x = pk2(t0, t1); pkr.y = pk2(t2, t3);
      *(uint2*)&d1[haloPx + cob] = pkr;   // n2reluT
    } else if (MODE == 2) {
      size_t base = (size_t)b * 65536 + (size_t)cob * 1024 + R * 32 + C;
#pragma unroll
      for (int r = 0; r < 4; ++r)
        outp[base + (size_t)r * 1024] = v[r] + xin[base + (size_t)r * 1024] * cmL[cob + r];
    } else {
      size_t base = (size_t)b * 65536 + (size_t)cob * 1024 + R * 32 + C;
#pragma unroll
      for (int r = 0; r < 4; ++r)
        outp[base + (size_t)r * 1024] += v[r];
    }
  }
}

extern "C" void kernel_launch(void* const* d_in, const int* in_sizes, int n_in,
                              void* d_out, int out_size, void* d_ws, size_t ws_size,
                              hipStream_t stream) {
  const float* x  = (const float*)d_in[0];
  const float* a1 = (const float*)d_in[1];
  const float* a2 = (const float*)d_in[2];
  const float* W1[4] = {(const float*)d_in[3], (const float*)d_in[5],
                        (const float*)d_in[7], (const float*)d_in[9]};
  const float* W2[4] = {(const float*)d_in[4], (const float*)d_in[6],
                        (const float*)d_in[8], (const float*)d_in[10]};
  float* out = (float*)d_out;
  char* ws = (char*)d_ws;
  const size_t HB = (size_t)IMST * 64 * 2;  // 9,469,952 B per halo buffer
  u16* xT  = (u16*)ws;
  u16* t   = (u16*)(ws + HB);
  u16* n1T = (u16*)(ws + 2 * HB);
  u16* n1r = (u16*)(ws + 3 * HB);
  u16* n2r = (u16*)(ws + 4 * HB);
  char* p = ws + 5 * HB;
  float* st  = (float*)p;            p += 8256 * 4;
  u16* wT1   = (u16*)p;              p += 4 * 36864 * 2;
  u16* wG    = (u16*)p;              p += 4 * 49152 * 2;
  u16* wE    = (u16*)p;              p += 36864 * 2;
  float* pA  = (float*)p;            p += 1024 * 128 * 4;
  float* pC  = (float*)p;            // 1024*1024*4

  hipMemsetAsync(ws, 0, 5 * HB, stream);  // zero all halos (+interiors, overwritten)
  prep_cm_k<<<1, 64, 0, stream>>>(a1, a2, st);
  pack_wT1_k<<<36, 256, 0, stream>>>(W1[0], W1[1], W1[2], W1[3], wT1);
  pack_wG_k<<<dim3(96, 4), 256, 0, stream>>>(W2[0], W2[1], W2[2], W2[3], wG);
  transpose_k<<<1024, 256, 0, stream>>>(x, xT);

  dim3 gs(16, 64);
  const u16* ins[4] = {xT, xT, n1r, n2r};
  for (int e = 0; e < 4; ++e) {
    convA_k<<<gs, 256, 0, stream>>>(ins[e], wT1 + e * 36864, t, pA);
    reducerA_k<<<1, 128, 0, stream>>>(pA, a1, st);
    renorm_k<<<2048, 256, 0, stream>>>(t, st);
    convC_k<<<gs, 512, 0, stream>>>(t, wG + e * 49152, pC);
    reducerC_k<<<1, 1024, 0, stream>>>(pC, st);
    prepE_k<<<9, 256, 0, stream>>>(W2[e], st, a2, wE);
    if (e == 0) {
      convE_k<0><<<gs, 256, 0, stream>>>(t, st, wE, nullptr, nullptr, n1T, n1r);
    } else if (e == 1) {
      convE_k<1><<<gs, 256, 0, stream>>>(t, st, wE, nullptr, nullptr, n2r, n1T);
    } else if (e == 2) {
      convE_k<2><<<gs, 256, 0, stream>>>(t, st, wE, out, x, nullptr, nullptr);
    } else {
      convE_k<3><<<gs, 256, 0, stream>>>(t, st, wE, out, nullptr, nullptr, nullptr);
    }
  }
}

// Round 5
// 845.856 us; speedup vs baseline: 1.3092x; 1.3092x over previous
//
#include <hip/hip_runtime.h>

#define EPS 1e-5f
#define NRED 65536.0f   // B*H*W = 64*32*32
#define IMST 73984      // 34*34*64 halo image stride (elements)

typedef short bf16x8 __attribute__((ext_vector_type(8)));
typedef float f32x4 __attribute__((ext_vector_type(4)));
typedef unsigned short u16;

__device__ __forceinline__ u16 f2bf(float x) {  // RNE f32->bf16
  union { float f; unsigned u; } v; v.f = x;
  unsigned r = v.u + 0x7FFF + ((v.u >> 16) & 1);
  return (u16)(r >> 16);
}
__device__ __forceinline__ float bf2f(u16 h) {
  union { unsigned u; float f; } v; v.u = ((unsigned)h) << 16;
  return v.f;
}
__device__ __forceinline__ unsigned pk2(float a, float b) {
  return (unsigned)f2bf(a) | ((unsigned)f2bf(b) << 16);
}

// st layout (floats): [0,64) s1 | [64,128) b1 | [1792,1856) bias2[c] | [8192,8256) cm[c]

// wT1[e][tap][co][ci] bf16
__global__ void pack_wT1_k(const float* __restrict__ w0, const float* __restrict__ w1,
                           const float* __restrict__ w2, const float* __restrict__ w3,
                           u16* __restrict__ wT1) {
  int e = blockIdx.x / 9, tap = blockIdx.x % 9;
  const float* w = e == 0 ? w0 : e == 1 ? w1 : e == 2 ? w2 : w3;
  u16* dst = wT1 + e * 36864 + tap * 4096;
  for (int idx = threadIdx.x; idx < 4096; idx += 256) {
    int co = idx >> 6, ci = idx & 63;
    dst[idx] = f2bf(w[(co * 64 + ci) * 9 + tap]);
  }
}

// wG[e][g*12+ch*4+q][co][cig] bf16, zero where tap=ch*4+q > 8
__global__ void pack_wG_k(const float* __restrict__ w0, const float* __restrict__ w1,
                          const float* __restrict__ w2, const float* __restrict__ w3,
                          u16* __restrict__ wG) {
  int e = blockIdx.y;
  const float* w = e == 0 ? w0 : e == 1 ? w1 : e == 2 ? w2 : w3;
  int bx = blockIdx.x;              // g*12 + ch*4 + q
  int q = bx & 3, ch = (bx >> 2) % 3, g = bx / 12;
  int tap = ch * 4 + q;
  u16* dst = wG + e * 49152 + bx * 512;
  for (int idx = threadIdx.x; idx < 512; idx += 256) {
    int co = idx >> 3, cig = idx & 7;
    float v = (tap <= 8) ? w[(co * 64 + g * 8 + cig) * 9 + tap] : 0.f;
    dst[idx] = f2bf(v);
  }
}

// x (NCHW f32) -> xT = bf16(relu(x)) halo pixel-major. grid 1024, block 256.
__global__ __launch_bounds__(256) void transpose_k(const float* __restrict__ x,
                                                   u16* __restrict__ xT) {
  __shared__ __align__(16) u16 sh[64 * 72];
  const int tid = threadIdx.x;
  const int b = blockIdx.x >> 4, slab = blockIdx.x & 15;
  const int ln = tid & 63, w = tid >> 6;
  const float* xb = x + (size_t)b * 65536 + slab * 64;
#pragma unroll
  for (int i = 0; i < 16; ++i) {
    int ci = w + i * 4;
    float v = xb[ci * 1024 + ln];
    sh[ln * 72 + ci] = f2bf(fmaxf(v, 0.f));
  }
  __syncthreads();
  u16* dst = xT + (size_t)b * IMST;
#pragma unroll
  for (int j = 0; j < 2; ++j) {
    int idx = tid + j * 256;
    int p = idx >> 3, oct = idx & 7;
    int gp = slab * 64 + p;
    int R = gp >> 5, C = gp & 31;
    *(uint4*)&dst[((R + 1) * 34 + C + 1) * 64 + oct * 8] = *(const uint4*)&sh[p * 72 + oct * 8];
  }
}

// ---------------- convA: t = conv3x3(xin, W1) + per-block stats partials -----
// block 256 = 4 waves; grid (16 rowpairs, 64 b). B prefetched fully, A in
// batches of 6 -> ~20 loads in flight per wave (latency tolerance over occupancy).
__global__ __launch_bounds__(256) void convA_k(const u16* __restrict__ xin,
                                               const u16* __restrict__ wT,
                                               u16* __restrict__ t,
                                               float* __restrict__ pA) {
  __shared__ float sA[64], qA[64];
  const int tid = threadIdx.x;
  const int b = blockIdx.y;
  if (tid < 64) { sA[tid] = 0.f; qA[tid] = 0.f; }
  __syncthreads();
  const int lane = tid & 63, w = tid >> 6;
  const int ln = lane & 15, quad = lane >> 4;
  const int R = blockIdx.x * 2 + (w >> 1);
  const int C = (w & 1) * 16 + ln;
  const size_t baseB = (size_t)b * IMST + (size_t)(R * 34 + C) * 64 + quad * 8;
  bf16x8 B[9][2];
#pragma unroll
  for (int tap = 0; tap < 9; ++tap) {
    const u16* p = &xin[baseB + (size_t)((tap / 3) * 34 + tap % 3) * 64];
    B[tap][0] = *(const bf16x8*)p;
    B[tap][1] = *(const bf16x8*)(p + 32);
  }
  f32x4 acc[4];
#pragma unroll
  for (int mt = 0; mt < 4; ++mt) acc[mt] = (f32x4){0.f, 0.f, 0.f, 0.f};
#pragma unroll
  for (int mt = 0; mt < 4; ++mt) {
#pragma unroll
    for (int tr3 = 0; tr3 < 3; ++tr3) {
      bf16x8 A[3][2];
#pragma unroll
      for (int tc = 0; tc < 3; ++tc) {
        const u16* wp = &wT[(size_t)((tr3 * 3 + tc) * 64 + mt * 16 + ln) * 64 + quad * 8];
        A[tc][0] = *(const bf16x8*)wp;
        A[tc][1] = *(const bf16x8*)(wp + 32);
      }
#pragma unroll
      for (int tc = 0; tc < 3; ++tc) {
        acc[mt] = __builtin_amdgcn_mfma_f32_16x16x32_bf16(A[tc][0], B[tr3 * 3 + tc][0], acc[mt], 0, 0, 0);
        acc[mt] = __builtin_amdgcn_mfma_f32_16x16x32_bf16(A[tc][1], B[tr3 * 3 + tc][1], acc[mt], 0, 0, 0);
      }
    }
  }
  u16* tb = t + (size_t)b * IMST + (size_t)((R + 1) * 34 + C + 1) * 64;
#pragma unroll
  for (int mt = 0; mt < 4; ++mt) {
    uint2 pk;
    pk.x = pk2(acc[mt][0], acc[mt][1]);
    pk.y = pk2(acc[mt][2], acc[mt][3]);
    *(uint2*)&tb[mt * 16 + quad * 4] = pk;
#pragma unroll
    for (int r = 0; r < 4; ++r) {
      float v = acc[mt][r];
      float s = v, q = v * v;
      s += __shfl_xor(s, 1); q += __shfl_xor(q, 1);
      s += __shfl_xor(s, 2); q += __shfl_xor(q, 2);
      s += __shfl_xor(s, 4); q += __shfl_xor(q, 4);
      s += __shfl_xor(s, 8); q += __shfl_xor(q, 8);
      if (ln == 0) {
        atomicAdd(&sA[mt * 16 + quad * 4 + r], s);
        atomicAdd(&qA[mt * 16 + quad * 4 + r], q);
      }
    }
  }
  __syncthreads();
  const int blk = blockIdx.y * 16 + blockIdx.x;
  if (tid < 64) pA[tid * 1024 + blk] = sA[tid];
  else if (tid < 128) pA[tid * 1024 + blk] = qA[tid - 64];
}

// reducerA: grid(64) block c reduces rows c (sum) and 64+c (sumsq), coalesced.
__global__ __launch_bounds__(256) void reducerA_k(const float* __restrict__ pA,
                                                  const float* __restrict__ a1,
                                                  float* __restrict__ st) {
  const int tid = threadIdx.x, c = blockIdx.x;
  float s = 0.f, q = 0.f;
  for (int i = tid; i < 1024; i += 256) {
    s += pA[c * 1024 + i];
    q += pA[(64 + c) * 1024 + i];
  }
#pragma unroll
  for (int off = 32; off; off >>= 1) { s += __shfl_xor(s, off); q += __shfl_xor(q, off); }
  __shared__ float red[8];
  int wv = tid >> 6;
  if ((tid & 63) == 0) { red[wv] = s; red[4 + wv] = q; }
  __syncthreads();
  if (tid == 0) {
    float S = red[0] + red[1] + red[2] + red[3];
    float Q = red[4] + red[5] + red[6] + red[7];
    int g = c >> 3;
    float m = 0.f;
    for (int i = g; i < 8; ++i) m += a1[i];
    float mu = S * (1.f / NRED);
    float var = Q * (1.f / NRED) - mu * mu;
    float r = rsqrtf(var + EPS);
    st[c] = r * m;
    st[64 + c] = -mu * r * m;
  }
}

// renorm: t := bf16(t*s1[ci] + b1[ci]) interior only. grid 2048, block 256.
__global__ __launch_bounds__(256) void renorm_k(u16* __restrict__ t,
                                                const float* __restrict__ st) {
  __shared__ float s1L[64], b1L[64];
  int tid = threadIdx.x;
  if (tid < 64) { s1L[tid] = st[tid]; b1L[tid] = st[64 + tid]; }
  __syncthreads();
  int idx = blockIdx.x * 256 + tid;
  int b = idx >> 13, rem = idx & 8191;
  int p = rem >> 3, oct = rem & 7;
  int R = p >> 5, C = p & 31;
  u16* ptr = t + (size_t)b * IMST + (size_t)((R + 1) * 34 + C + 1) * 64 + oct * 8;
  uint4 u = *(const uint4*)ptr;
  unsigned vals[4] = {u.x, u.y, u.z, u.w};
  uint4 o;
  unsigned res[4];
#pragma unroll
  for (int i = 0; i < 4; ++i) {
    int ci = oct * 8 + i * 2;
    float lo = bf2f((u16)(vals[i] & 0xffff)) * s1L[ci] + b1L[ci];
    float hi = bf2f((u16)(vals[i] >> 16)) * s1L[ci + 1] + b1L[ci + 1];
    res[i] = pk2(lo, hi);
  }
  o.x = res[0]; o.y = res[1]; o.z = res[2]; o.w = res[3];
  *(uint4*)ptr = o;
}

// ---------------- convC: per-group prefix stats of conv2 ---------------------
// block 512 = 8 waves (nt = w&3 pxtile, ch2 = w>>2 co-half); grid (16, 64).
// All 24 B frags prefetched; A in batches of 6 per group.
__global__ __launch_bounds__(512) void convC_k(const u16* __restrict__ t,
                                               const u16* __restrict__ wG,
                                               float* __restrict__ pC) {
  __shared__ float sC[512], qC[512];
  const int tid = threadIdx.x;
  const int b = blockIdx.y;
  sC[tid] = 0.f; qC[tid] = 0.f;
  __syncthreads();
  const int lane = tid & 63, w = tid >> 6;
  const int ln = lane & 15, quad = lane >> 4;
  const int nt = w & 3, ch2 = w >> 2;
  const int R = blockIdx.x * 2 + (nt >> 1);
  const int C = (nt & 1) * 16 + ln;
  const size_t baseB = (size_t)b * IMST + (size_t)(R * 34 + C) * 64;
  size_t po[3];
#pragma unroll
  for (int ch = 0; ch < 3; ++ch) {
    int tp = ch * 4 + quad; if (tp > 8) tp = 8;  // A is zero there
    po[ch] = baseB + (size_t)((tp / 3) * 34 + tp % 3) * 64;
  }
  bf16x8 B[3][8];
#pragma unroll
  for (int ch = 0; ch < 3; ++ch)
#pragma unroll
    for (int g = 0; g < 8; ++g)
      B[ch][g] = *(const bf16x8*)&t[po[ch] + g * 8];
  f32x4 acc[8][2];
#pragma unroll
  for (int g = 0; g < 8; ++g)
#pragma unroll
    for (int m = 0; m < 2; ++m) acc[g][m] = (f32x4){0.f, 0.f, 0.f, 0.f};
#pragma unroll
  for (int g = 0; g < 8; ++g) {
    bf16x8 A[3][2];
#pragma unroll
    for (int ch = 0; ch < 3; ++ch)
#pragma unroll
      for (int mtl = 0; mtl < 2; ++mtl)
        A[ch][mtl] = *(const bf16x8*)&wG[((g * 12 + ch * 4 + quad) * 64 + ch2 * 32 + mtl * 16 + ln) * 8];
#pragma unroll
    for (int ch = 0; ch < 3; ++ch)
#pragma unroll
      for (int mtl = 0; mtl < 2; ++mtl)
        acc[g][mtl] = __builtin_amdgcn_mfma_f32_16x16x32_bf16(A[ch][mtl], B[ch][g], acc[g][mtl], 0, 0, 0);
  }
  f32x4 P[2];
  P[0] = (f32x4){0.f, 0.f, 0.f, 0.f};
  P[1] = (f32x4){0.f, 0.f, 0.f, 0.f};
#pragma unroll
  for (int k = 0; k < 8; ++k) {
    P[0] += acc[k][0]; P[1] += acc[k][1];
#pragma unroll
    for (int mtl = 0; mtl < 2; ++mtl) {
#pragma unroll
      for (int r = 0; r < 4; ++r) {
        float s = P[mtl][r], q = s * s;
        s += __shfl_xor(s, 1); q += __shfl_xor(q, 1);
        s += __shfl_xor(s, 2); q += __shfl_xor(q, 2);
        s += __shfl_xor(s, 4); q += __shfl_xor(q, 4);
        s += __shfl_xor(s, 8); q += __shfl_xor(q, 8);
        if (ln == 0) {
          int co = ch2 * 32 + mtl * 16 + quad * 4 + r;
          atomicAdd(&sC[k * 64 + co], s);
          atomicAdd(&qC[k * 64 + co], q);
        }
      }
    }
  }
  __syncthreads();
  const int blk = blockIdx.y * 16 + blockIdx.x;
  pC[tid * 1024 + blk] = sC[tid];
  pC[(512 + tid) * 1024 + blk] = qC[tid];
}

// redCprepE: grid(64) block c: reduce per-(k,c) stats (coalesced rows), then
// finalizeC + fold g into wE[tap][co=c][ci]; bias2 -> st[1792+c], cm -> st[8192+c].
__global__ __launch_bounds__(256) void redCprepE_k(const float* __restrict__ pC,
                                                   const float* __restrict__ w2,
                                                   const float* __restrict__ a1,
                                                   const float* __restrict__ a2,
                                                   float* __restrict__ st,
                                                   u16* __restrict__ wE) {
  const int tid = threadIdx.x, c = blockIdx.x;
  float s[8], q[8];
#pragma unroll
  for (int k = 0; k < 8; ++k) { s[k] = 0.f; q[k] = 0.f; }
  for (int i = tid; i < 1024; i += 256) {
#pragma unroll
    for (int k = 0; k < 8; ++k) {
      s[k] += pC[(k * 64 + c) * 1024 + i];
      q[k] += pC[(512 + k * 64 + c) * 1024 + i];
    }
  }
#pragma unroll
  for (int k = 0; k < 8; ++k) {
#pragma unroll
    for (int off = 32; off; off >>= 1) { s[k] += __shfl_xor(s[k], off); q[k] += __shfl_xor(q[k], off); }
  }
  __shared__ float red[4][16];
  __shared__ float gL[8];
  int wv = tid >> 6;
  if ((tid & 63) == 0) {
#pragma unroll
    for (int k = 0; k < 8; ++k) { red[wv][k * 2] = s[k]; red[wv][k * 2 + 1] = q[k]; }
  }
  __syncthreads();
  if (tid == 0) {
    float suf = 0.f, bias = 0.f;
    for (int k = 7; k >= 0; --k) {
      float S = red[0][k * 2] + red[1][k * 2] + red[2][k * 2] + red[3][k * 2];
      float Q = red[0][k * 2 + 1] + red[1][k * 2 + 1] + red[2][k * 2 + 1] + red[3][k * 2 + 1];
      float mu = S * (1.f / NRED);
      float var = Q * (1.f / NRED) - mu * mu;
      float rr = rsqrtf(var + EPS);
      bias -= a2[k] * mu * rr;
      suf += a2[k] * rr;
      gL[k] = suf;
    }
    st[1792 + c] = bias;
    int g = c >> 3;
    float m1 = 0.f, m2 = 0.f;
    for (int i = g; i < 8; ++i) { m1 += a1[i]; m2 += a2[i]; }
    st[8192 + c] = m1 * m2;
  }
  __syncthreads();
  for (int idx = tid; idx < 576; idx += 256) {
    int tap = idx >> 6, ci = idx & 63;
    wE[(tap * 64 + c) * 64 + ci] = f2bf(w2[(c * 64 + ci) * 9 + tap] * gL[ci >> 3]);
  }
}

// ---------------- convE: mixed conv2 + fused epilogue ------------------------
// block 256 = 4 waves; grid (16, 64). Same prefetch structure as convA.
// MODE 0: n1T/n1reluT | 1: n2reluT = relu(v + pool(n1T)*cm) | 2: out = v + x*cm | 3: out += v
template <int MODE>
__global__ __launch_bounds__(256) void convE_k(const u16* __restrict__ t,
                                               const float* __restrict__ st,
                                               const u16* __restrict__ wE,
                                               float* __restrict__ outp,
                                               const float* __restrict__ xin,
                                               u16* __restrict__ d1,
                                               u16* __restrict__ d2) {
  __shared__ float cmL[64], biasL[64];
  const int tid = threadIdx.x;
  const int b = blockIdx.y;
  if (tid < 64) { cmL[tid] = st[8192 + tid]; biasL[tid] = st[1792 + tid]; }
  __syncthreads();
  const int lane = tid & 63, w = tid >> 6;
  const int ln = lane & 15, quad = lane >> 4;
  const int R = blockIdx.x * 2 + (w >> 1);
  const int C = (w & 1) * 16 + ln;
  const size_t baseB = (size_t)b * IMST + (size_t)(R * 34 + C) * 64 + quad * 8;
  bf16x8 B[9][2];
#pragma unroll
  for (int tap = 0; tap < 9; ++tap) {
    const u16* p = &t[baseB + (size_t)((tap / 3) * 34 + tap % 3) * 64];
    B[tap][0] = *(const bf16x8*)p;
    B[tap][1] = *(const bf16x8*)(p + 32);
  }
  f32x4 acc[4];
#pragma unroll
  for (int mt = 0; mt < 4; ++mt) acc[mt] = (f32x4){0.f, 0.f, 0.f, 0.f};
#pragma unroll
  for (int mt = 0; mt < 4; ++mt) {
#pragma unroll
    for (int tr3 = 0; tr3 < 3; ++tr3) {
      bf16x8 A[3][2];
#pragma unroll
      for (int tc = 0; tc < 3; ++tc) {
        const u16* wp = &wE[(size_t)((tr3 * 3 + tc) * 64 + mt * 16 + ln) * 64 + quad * 8];
        A[tc][0] = *(const bf16x8*)wp;
        A[tc][1] = *(const bf16x8*)(wp + 32);
      }
#pragma unroll
      for (int tc = 0; tc < 3; ++tc) {
        acc[mt] = __builtin_amdgcn_mfma_f32_16x16x32_bf16(A[tc][0], B[tr3 * 3 + tc][0], acc[mt], 0, 0, 0);
        acc[mt] = __builtin_amdgcn_mfma_f32_16x16x32_bf16(A[tc][1], B[tr3 * 3 + tc][1], acc[mt], 0, 0, 0);
      }
    }
  }
  const size_t haloPx = (size_t)b * IMST + (size_t)((R + 1) * 34 + C + 1) * 64;
#pragma unroll
  for (int mt = 0; mt < 4; ++mt) {
    int cob = mt * 16 + quad * 4;
    float v[4];
#pragma unroll
    for (int r = 0; r < 4; ++r) v[r] = acc[mt][r] + biasL[cob + r];
    if (MODE == 0) {
      uint2 pk, pkr;
      pk.x = pk2(v[0], v[1]); pk.y = pk2(v[2], v[3]);
      pkr.x = pk2(fmaxf(v[0], 0.f), fmaxf(v[1], 0.f));
      pkr.y = pk2(fmaxf(v[2], 0.f), fmaxf(v[3], 0.f));
      *(uint2*)&d1[haloPx + cob] = pk;    // n1T (raw, for pool)
      *(uint2*)&d2[haloPx + cob] = pkr;   // n1reluT (for e2 convA)
    } else if (MODE == 1) {
      float ps[4] = {0.f, 0.f, 0.f, 0.f};
      const size_t pb = (size_t)b * IMST + (size_t)(R * 34 + C) * 64 + cob;
#pragma unroll
      for (int dy = 0; dy < 3; ++dy)
#pragma unroll
        for (int dx = 0; dx < 3; ++dx) {
          uint2 u = *(const uint2*)&d2[pb + (size_t)(dy * 34 + dx) * 64];  // d2 = n1T
          ps[0] += bf2f((u16)(u.x & 0xffff));
          ps[1] += bf2f((u16)(u.x >> 16));
          ps[2] += bf2f((u16)(u.y & 0xffff));
          ps[3] += bf2f((u16)(u.y >> 16));
        }
      float rows = 3.f - (R == 0 ? 1.f : 0.f) - (R == 31 ? 1.f : 0.f);
      float cols = 3.f - (C == 0 ? 1.f : 0.f) - (C == 31 ? 1.f : 0.f);
      float inv = 1.f / (rows * cols);
      uint2 pkr;
      float t0 = fmaxf(v[0] + ps[0] * inv * cmL[cob], 0.f);
      float t1 = fmaxf(v[1] + ps[1] * inv * cmL[cob + 1], 0.f);
      float t2 = fmaxf(v[2] + ps[2] * inv * cmL[cob + 2], 0.f);
      float t3 = fmaxf(v[3] + ps[3] * inv * cmL[cob + 3], 0.f);
      pkr.x = pk2(t0, t1); pkr.y = pk2(t2, t3);
      *(uint2*)&d1[haloPx + cob] = pkr;   // n2reluT
    } else if (MODE == 2) {
      size_t base = (size_t)b * 65536 + (size_t)cob * 1024 + R * 32 + C;
#pragma unroll
      for (int r = 0; r < 4; ++r)
        outp[base + (size_t)r * 1024] = v[r] + xin[base + (size_t)r * 1024] * cmL[cob + r];
    } else {
      size_t base = (size_t)b * 65536 + (size_t)cob * 1024 + R * 32 + C;
#pragma unroll
      for (int r = 0; r < 4; ++r)
        outp[base + (size_t)r * 1024] += v[r];
    }
  }
}

extern "C" void kernel_launch(void* const* d_in, const int* in_sizes, int n_in,
                              void* d_out, int out_size, void* d_ws, size_t ws_size,
                              hipStream_t stream) {
  const float* x  = (const float*)d_in[0];
  const float* a1 = (const float*)d_in[1];
  const float* a2 = (const float*)d_in[2];
  const float* W1[4] = {(const float*)d_in[3], (const float*)d_in[5],
                        (const float*)d_in[7], (const float*)d_in[9]};
  const float* W2[4] = {(const float*)d_in[4], (const float*)d_in[6],
                        (const float*)d_in[8], (const float*)d_in[10]};
  float* out = (float*)d_out;
  char* ws = (char*)d_ws;
  const size_t HB = (size_t)IMST * 64 * 2;  // 9,469,952 B per halo buffer
  u16* xT  = (u16*)ws;
  u16* t   = (u16*)(ws + HB);
  u16* n1T = (u16*)(ws + 2 * HB);
  u16* n1r = (u16*)(ws + 3 * HB);
  u16* n2r = (u16*)(ws + 4 * HB);
  char* p = ws + 5 * HB;
  float* st  = (float*)p;            p += 8256 * 4;
  u16* wT1   = (u16*)p;              p += 4 * 36864 * 2;
  u16* wG    = (u16*)p;              p += 4 * 49152 * 2;
  u16* wE    = (u16*)p;              p += 36864 * 2;
  float* pA  = (float*)p;            p += 128 * 1024 * 4;
  float* pC  = (float*)p;            // 1024*1024*4

  hipMemsetAsync(ws, 0, 5 * HB, stream);  // zero halos (+interiors, overwritten)
  pack_wT1_k<<<36, 256, 0, stream>>>(W1[0], W1[1], W1[2], W1[3], wT1);
  pack_wG_k<<<dim3(96, 4), 256, 0, stream>>>(W2[0], W2[1], W2[2], W2[3], wG);
  transpose_k<<<1024, 256, 0, stream>>>(x, xT);

  dim3 gs(16, 64);
  const u16* ins[4] = {xT, xT, n1r, n2r};
  for (int e = 0; e < 4; ++e) {
    convA_k<<<gs, 256, 0, stream>>>(ins[e], wT1 + e * 36864, t, pA);
    reducerA_k<<<64, 256, 0, stream>>>(pA, a1, st);
    renorm_k<<<2048, 256, 0, stream>>>(t, st);
    convC_k<<<gs, 512, 0, stream>>>(t, wG + e * 49152, pC);
    redCprepE_k<<<64, 256, 0, stream>>>(pC, W2[e], a1, a2, st, wE);
    if (e == 0) {
      convE_k<0><<<gs, 256, 0, stream>>>(t, st, wE, nullptr, nullptr, n1T, n1r);
    } else if (e == 1) {
      convE_k<1><<<gs, 256, 0, stream>>>(t, st, wE, nullptr, nullptr, n2r, n1T);
    } else if (e == 2) {
      convE_k<2><<<gs, 256, 0, stream>>>(t, st, wE, out, x, nullptr, nullptr);
    } else {
      convE_k<3><<<gs, 256, 0, stream>>>(t, st, wE, out, nullptr, nullptr, nullptr);
    }
  }
}

// Round 6
// 759.595 us; speedup vs baseline: 1.4579x; 1.1136x over previous
//
#include <hip/hip_runtime.h>

#define EPS 1e-5f
#define NRED 65536.0f   // B*H*W = 64*32*32
#define IMST 73984      // 34*34*64 halo image stride (elements)

typedef short bf16x8 __attribute__((ext_vector_type(8)));
typedef float f32x4 __attribute__((ext_vector_type(4)));
typedef unsigned short u16;

__device__ __forceinline__ u16 f2bf(float x) {  // RNE f32->bf16
  union { float f; unsigned u; } v; v.f = x;
  unsigned r = v.u + 0x7FFF + ((v.u >> 16) & 1);
  return (u16)(r >> 16);
}
__device__ __forceinline__ float bf2f(u16 h) {
  union { unsigned u; float f; } v; v.u = ((unsigned)h) << 16;
  return v.f;
}
__device__ __forceinline__ unsigned pk2(float a, float b) {
  return (unsigned)f2bf(a) | ((unsigned)f2bf(b) << 16);
}

// DPP row-shift reduce over the 16-lane DPP row (ln = lane&15). Sum lands in
// ln==15 of each row. Pure VALU (no LDS pipe, no lgkmcnt) — replaces
// __shfl_xor which lowers to ds_bpermute and serializes on LDS latency.
template <int CTRL>
__device__ __forceinline__ float dpp_mov(float x) {
  int xi = __builtin_bit_cast(int, x);
  int r = __builtin_amdgcn_update_dpp(0, xi, CTRL, 0xF, 0xF, true);
  return __builtin_bit_cast(float, r);
}
__device__ __forceinline__ float row_reduce16(float x) {
  x += dpp_mov<0x111>(x);  // row_shr:1
  x += dpp_mov<0x112>(x);  // row_shr:2
  x += dpp_mov<0x114>(x);  // row_shr:4
  x += dpp_mov<0x118>(x);  // row_shr:8
  return x;                // valid in ln==15
}

// st layout (floats): [0,64) s1 | [64,128) b1 | [1792,1856) bias2[c] | [8192,8256) cm[c]

// wT1[e][tap][co][ci] bf16
__global__ void pack_wT1_k(const float* __restrict__ w0, const float* __restrict__ w1,
                           const float* __restrict__ w2, const float* __restrict__ w3,
                           u16* __restrict__ wT1) {
  int e = blockIdx.x / 9, tap = blockIdx.x % 9;
  const float* w = e == 0 ? w0 : e == 1 ? w1 : e == 2 ? w2 : w3;
  u16* dst = wT1 + e * 36864 + tap * 4096;
  for (int idx = threadIdx.x; idx < 4096; idx += 256) {
    int co = idx >> 6, ci = idx & 63;
    dst[idx] = f2bf(w[(co * 64 + ci) * 9 + tap]);
  }
}

// wG[e][g*12+ch*4+q][co][cig] bf16, zero where tap=ch*4+q > 8
__global__ void pack_wG_k(const float* __restrict__ w0, const float* __restrict__ w1,
                          const float* __restrict__ w2, const float* __restrict__ w3,
                          u16* __restrict__ wG) {
  int e = blockIdx.y;
  const float* w = e == 0 ? w0 : e == 1 ? w1 : e == 2 ? w2 : w3;
  int bx = blockIdx.x;              // g*12 + ch*4 + q
  int q = bx & 3, ch = (bx >> 2) % 3, g = bx / 12;
  int tap = ch * 4 + q;
  u16* dst = wG + e * 49152 + bx * 512;
  for (int idx = threadIdx.x; idx < 512; idx += 256) {
    int co = idx >> 3, cig = idx & 7;
    float v = (tap <= 8) ? w[(co * 64 + g * 8 + cig) * 9 + tap] : 0.f;
    dst[idx] = f2bf(v);
  }
}

// x (NCHW f32) -> xT = bf16(relu(x)) halo pixel-major. grid 1024, block 256.
__global__ __launch_bounds__(256) void transpose_k(const float* __restrict__ x,
                                                   u16* __restrict__ xT) {
  __shared__ __align__(16) u16 sh[64 * 72];
  const int tid = threadIdx.x;
  const int b = blockIdx.x >> 4, slab = blockIdx.x & 15;
  const int ln = tid & 63, w = tid >> 6;
  const float* xb = x + (size_t)b * 65536 + slab * 64;
#pragma unroll
  for (int i = 0; i < 16; ++i) {
    int ci = w + i * 4;
    float v = xb[ci * 1024 + ln];
    sh[ln * 72 + ci] = f2bf(fmaxf(v, 0.f));
  }
  __syncthreads();
  u16* dst = xT + (size_t)b * IMST;
#pragma unroll
  for (int j = 0; j < 2; ++j) {
    int idx = tid + j * 256;
    int p = idx >> 3, oct = idx & 7;
    int gp = slab * 64 + p;
    int R = gp >> 5, C = gp & 31;
    *(uint4*)&dst[((R + 1) * 34 + C + 1) * 64 + oct * 8] = *(const uint4*)&sh[p * 72 + oct * 8];
  }
}

// ---------------- convA: t = conv3x3(xin, W1) + per-block stats partials -----
// block 256 = 4 waves; grid (16 rowpairs, 64 b)
__global__ __launch_bounds__(256) void convA_k(const u16* __restrict__ xin,
                                               const u16* __restrict__ wT,
                                               u16* __restrict__ t,
                                               float* __restrict__ pA) {
  __shared__ float sA[64], qA[64];
  const int tid = threadIdx.x;
  const int b = blockIdx.y;
  if (tid < 64) { sA[tid] = 0.f; qA[tid] = 0.f; }
  __syncthreads();
  const int lane = tid & 63, w = tid >> 6;
  const int ln = lane & 15, quad = lane >> 4;
  const int R = blockIdx.x * 2 + (w >> 1);
  const int C = (w & 1) * 16 + ln;
  const size_t baseB = (size_t)b * IMST + (size_t)(R * 34 + C) * 64 + quad * 8;
  bf16x8 B[9][2];
#pragma unroll
  for (int tap = 0; tap < 9; ++tap) {
    const u16* p = &xin[baseB + (size_t)((tap / 3) * 34 + tap % 3) * 64];
    B[tap][0] = *(const bf16x8*)p;
    B[tap][1] = *(const bf16x8*)(p + 32);
  }
  f32x4 acc[4];
#pragma unroll
  for (int mt = 0; mt < 4; ++mt) acc[mt] = (f32x4){0.f, 0.f, 0.f, 0.f};
#pragma unroll
  for (int mt = 0; mt < 4; ++mt) {
#pragma unroll
    for (int tr3 = 0; tr3 < 3; ++tr3) {
      bf16x8 A[3][2];
#pragma unroll
      for (int tc = 0; tc < 3; ++tc) {
        const u16* wp = &wT[(size_t)((tr3 * 3 + tc) * 64 + mt * 16 + ln) * 64 + quad * 8];
        A[tc][0] = *(const bf16x8*)wp;
        A[tc][1] = *(const bf16x8*)(wp + 32);
      }
#pragma unroll
      for (int tc = 0; tc < 3; ++tc) {
        acc[mt] = __builtin_amdgcn_mfma_f32_16x16x32_bf16(A[tc][0], B[tr3 * 3 + tc][0], acc[mt], 0, 0, 0);
        acc[mt] = __builtin_amdgcn_mfma_f32_16x16x32_bf16(A[tc][1], B[tr3 * 3 + tc][1], acc[mt], 0, 0, 0);
      }
    }
  }
  u16* tb = t + (size_t)b * IMST + (size_t)((R + 1) * 34 + C + 1) * 64;
#pragma unroll
  for (int mt = 0; mt < 4; ++mt) {
    uint2 pk;
    pk.x = pk2(acc[mt][0], acc[mt][1]);
    pk.y = pk2(acc[mt][2], acc[mt][3]);
    *(uint2*)&tb[mt * 16 + quad * 4] = pk;
#pragma unroll
    for (int r = 0; r < 4; ++r) {
      float v = acc[mt][r];
      float s = row_reduce16(v);
      float q = row_reduce16(v * v);
      if (ln == 15) {
        atomicAdd(&sA[mt * 16 + quad * 4 + r], s);
        atomicAdd(&qA[mt * 16 + quad * 4 + r], q);
      }
    }
  }
  __syncthreads();
  const int blk = blockIdx.y * 16 + blockIdx.x;
  if (tid < 64) pA[blk * 128 + tid] = sA[tid];              // coalesced
  else if (tid < 128) pA[blk * 128 + tid] = qA[tid - 64];
}

// reducerA: grid(64); block c reduces pA[*][c] / pA[*][64+c] (strided reads, L2-hot)
__global__ __launch_bounds__(256) void reducerA_k(const float* __restrict__ pA,
                                                  const float* __restrict__ a1,
                                                  float* __restrict__ st) {
  const int tid = threadIdx.x, c = blockIdx.x;
  float s = 0.f, q = 0.f;
  for (int i = tid; i < 1024; i += 256) {
    s += pA[i * 128 + c];
    q += pA[i * 128 + 64 + c];
  }
#pragma unroll
  for (int off = 32; off; off >>= 1) { s += __shfl_xor(s, off); q += __shfl_xor(q, off); }
  __shared__ float red[8];
  int wv = tid >> 6;
  if ((tid & 63) == 0) { red[wv] = s; red[4 + wv] = q; }
  __syncthreads();
  if (tid == 0) {
    float S = red[0] + red[1] + red[2] + red[3];
    float Q = red[4] + red[5] + red[6] + red[7];
    int g = c >> 3;
    float m = 0.f;
    for (int i = g; i < 8; ++i) m += a1[i];
    float mu = S * (1.f / NRED);
    float var = Q * (1.f / NRED) - mu * mu;
    float r = rsqrtf(var + EPS);
    st[c] = r * m;
    st[64 + c] = -mu * r * m;
  }
}

// renorm: t := bf16(t*s1[ci] + b1[ci]) interior only. grid 2048, block 256.
__global__ __launch_bounds__(256) void renorm_k(u16* __restrict__ t,
                                                const float* __restrict__ st) {
  __shared__ float s1L[64], b1L[64];
  int tid = threadIdx.x;
  if (tid < 64) { s1L[tid] = st[tid]; b1L[tid] = st[64 + tid]; }
  __syncthreads();
  int idx = blockIdx.x * 256 + tid;
  int b = idx >> 13, rem = idx & 8191;
  int p = rem >> 3, oct = rem & 7;
  int R = p >> 5, C = p & 31;
  u16* ptr = t + (size_t)b * IMST + (size_t)((R + 1) * 34 + C + 1) * 64 + oct * 8;
  uint4 u = *(const uint4*)ptr;
  unsigned vals[4] = {u.x, u.y, u.z, u.w};
  uint4 o;
  unsigned res[4];
#pragma unroll
  for (int i = 0; i < 4; ++i) {
    int ci = oct * 8 + i * 2;
    float lo = bf2f((u16)(vals[i] & 0xffff)) * s1L[ci] + b1L[ci];
    float hi = bf2f((u16)(vals[i] >> 16)) * s1L[ci + 1] + b1L[ci + 1];
    res[i] = pk2(lo, hi);
  }
  o.x = res[0]; o.y = res[1]; o.z = res[2]; o.w = res[3];
  *(uint4*)ptr = o;
}

// ---------------- convC: per-group prefix stats of conv2 ---------------------
// block 512 = 8 waves (nt = w&3 pxtile, ch2 = w>>2 co-half); grid (16, 64).
__global__ __launch_bounds__(512) void convC_k(const u16* __restrict__ t,
                                               const u16* __restrict__ wG,
                                               float* __restrict__ pC) {
  __shared__ float sC[512], qC[512];
  const int tid = threadIdx.x;
  const int b = blockIdx.y;
  sC[tid] = 0.f; qC[tid] = 0.f;
  __syncthreads();
  const int lane = tid & 63, w = tid >> 6;
  const int ln = lane & 15, quad = lane >> 4;
  const int nt = w & 3, ch2 = w >> 2;
  const int R = blockIdx.x * 2 + (nt >> 1);
  const int C = (nt & 1) * 16 + ln;
  const size_t baseB = (size_t)b * IMST + (size_t)(R * 34 + C) * 64;
  size_t po[3];
#pragma unroll
  for (int ch = 0; ch < 3; ++ch) {
    int tp = ch * 4 + quad; if (tp > 8) tp = 8;  // A is zero there
    po[ch] = baseB + (size_t)((tp / 3) * 34 + tp % 3) * 64;
  }
  bf16x8 B[3][8];
#pragma unroll
  for (int ch = 0; ch < 3; ++ch)
#pragma unroll
    for (int g = 0; g < 8; ++g)
      B[ch][g] = *(const bf16x8*)&t[po[ch] + g * 8];
  f32x4 acc[8][2];
#pragma unroll
  for (int g = 0; g < 8; ++g)
#pragma unroll
    for (int m = 0; m < 2; ++m) acc[g][m] = (f32x4){0.f, 0.f, 0.f, 0.f};
#pragma unroll
  for (int g = 0; g < 8; ++g) {
    bf16x8 A[3][2];
#pragma unroll
    for (int ch = 0; ch < 3; ++ch)
#pragma unroll
      for (int mtl = 0; mtl < 2; ++mtl)
        A[ch][mtl] = *(const bf16x8*)&wG[((g * 12 + ch * 4 + quad) * 64 + ch2 * 32 + mtl * 16 + ln) * 8];
#pragma unroll
    for (int ch = 0; ch < 3; ++ch)
#pragma unroll
      for (int mtl = 0; mtl < 2; ++mtl)
        acc[g][mtl] = __builtin_amdgcn_mfma_f32_16x16x32_bf16(A[ch][mtl], B[ch][g], acc[g][mtl], 0, 0, 0);
  }
  f32x4 P[2];
  P[0] = (f32x4){0.f, 0.f, 0.f, 0.f};
  P[1] = (f32x4){0.f, 0.f, 0.f, 0.f};
#pragma unroll
  for (int k = 0; k < 8; ++k) {
    P[0] += acc[k][0]; P[1] += acc[k][1];
#pragma unroll
    for (int mtl = 0; mtl < 2; ++mtl) {
#pragma unroll
      for (int r = 0; r < 4; ++r) {
        float v = P[mtl][r];
        float s = row_reduce16(v);
        float q = row_reduce16(v * v);
        if (ln == 15) {
          int co = ch2 * 32 + mtl * 16 + quad * 4 + r;
          atomicAdd(&sC[k * 64 + co], s);
          atomicAdd(&qC[k * 64 + co], q);
        }
      }
    }
  }
  __syncthreads();
  const int blk = blockIdx.y * 16 + blockIdx.x;
  pC[blk * 1024 + tid] = sC[tid];                 // coalesced
  pC[blk * 1024 + 512 + tid] = qC[tid];
}

// redCprepE: grid(64) block c: reduce per-(k,c) stats, then finalizeC + fold g
// into wE[tap][co=c][ci]; bias2 -> st[1792+c], cm -> st[8192+c].
__global__ __launch_bounds__(256) void redCprepE_k(const float* __restrict__ pC,
                                                   const float* __restrict__ w2,
                                                   const float* __restrict__ a1,
                                                   const float* __restrict__ a2,
                                                   float* __restrict__ st,
                                                   u16* __restrict__ wE) {
  const int tid = threadIdx.x, c = blockIdx.x;
  float s[8], q[8];
#pragma unroll
  for (int k = 0; k < 8; ++k) { s[k] = 0.f; q[k] = 0.f; }
  for (int i = tid; i < 1024; i += 256) {
#pragma unroll
    for (int k = 0; k < 8; ++k) {
      s[k] += pC[i * 1024 + k * 64 + c];
      q[k] += pC[i * 1024 + 512 + k * 64 + c];
    }
  }
#pragma unroll
  for (int k = 0; k < 8; ++k) {
#pragma unroll
    for (int off = 32; off; off >>= 1) { s[k] += __shfl_xor(s[k], off); q[k] += __shfl_xor(q[k], off); }
  }
  __shared__ float red[4][16];
  __shared__ float gL[8];
  int wv = tid >> 6;
  if ((tid & 63) == 0) {
#pragma unroll
    for (int k = 0; k < 8; ++k) { red[wv][k * 2] = s[k]; red[wv][k * 2 + 1] = q[k]; }
  }
  __syncthreads();
  if (tid == 0) {
    float suf = 0.f, bias = 0.f;
    for (int k = 7; k >= 0; --k) {
      float S = red[0][k * 2] + red[1][k * 2] + red[2][k * 2] + red[3][k * 2];
      float Q = red[0][k * 2 + 1] + red[1][k * 2 + 1] + red[2][k * 2 + 1] + red[3][k * 2 + 1];
      float mu = S * (1.f / NRED);
      float var = Q * (1.f / NRED) - mu * mu;
      float rr = rsqrtf(var + EPS);
      bias -= a2[k] * mu * rr;
      suf += a2[k] * rr;
      gL[k] = suf;
    }
    st[1792 + c] = bias;
    int g = c >> 3;
    float m1 = 0.f, m2 = 0.f;
    for (int i = g; i < 8; ++i) { m1 += a1[i]; m2 += a2[i]; }
    st[8192 + c] = m1 * m2;
  }
  __syncthreads();
  for (int idx = tid; idx < 576; idx += 256) {
    int tap = idx >> 6, ci = idx & 63;
    wE[(tap * 64 + c) * 64 + ci] = f2bf(w2[(c * 64 + ci) * 9 + tap] * gL[ci >> 3]);
  }
}

// ---------------- convE: mixed conv2 + fused epilogue ------------------------
// block 256 = 4 waves; grid (16, 64).
// MODE 0: n1T/n1reluT | 1: n2reluT = relu(v + pool(n1T)*cm) | 2: out = v + x*cm | 3: out += v
template <int MODE>
__global__ __launch_bounds__(256) void convE_k(const u16* __restrict__ t,
                                               const float* __restrict__ st,
                                               const u16* __restrict__ wE,
                                               float* __restrict__ outp,
                                               const float* __restrict__ xin,
                                               u16* __restrict__ d1,
                                               u16* __restrict__ d2) {
  __shared__ float cmL[64], biasL[64];
  const int tid = threadIdx.x;
  const int b = blockIdx.y;
  if (tid < 64) { cmL[tid] = st[8192 + tid]; biasL[tid] = st[1792 + tid]; }
  __syncthreads();
  const int lane = tid & 63, w = tid >> 6;
  const int ln = lane & 15, quad = lane >> 4;
  const int R = blockIdx.x * 2 + (w >> 1);
  const int C = (w & 1) * 16 + ln;
  const size_t baseB = (size_t)b * IMST + (size_t)(R * 34 + C) * 64 + quad * 8;
  bf16x8 B[9][2];
#pragma unroll
  for (int tap = 0; tap < 9; ++tap) {
    const u16* p = &t[baseB + (size_t)((tap / 3) * 34 + tap % 3) * 64];
    B[tap][0] = *(const bf16x8*)p;
    B[tap][1] = *(const bf16x8*)(p + 32);
  }
  f32x4 acc[4];
#pragma unroll
  for (int mt = 0; mt < 4; ++mt) acc[mt] = (f32x4){0.f, 0.f, 0.f, 0.f};
#pragma unroll
  for (int mt = 0; mt < 4; ++mt) {
#pragma unroll
    for (int tr3 = 0; tr3 < 3; ++tr3) {
      bf16x8 A[3][2];
#pragma unroll
      for (int tc = 0; tc < 3; ++tc) {
        const u16* wp = &wE[(size_t)((tr3 * 3 + tc) * 64 + mt * 16 + ln) * 64 + quad * 8];
        A[tc][0] = *(const bf16x8*)wp;
        A[tc][1] = *(const bf16x8*)(wp + 32);
      }
#pragma unroll
      for (int tc = 0; tc < 3; ++tc) {
        acc[mt] = __builtin_amdgcn_mfma_f32_16x16x32_bf16(A[tc][0], B[tr3 * 3 + tc][0], acc[mt], 0, 0, 0);
        acc[mt] = __builtin_amdgcn_mfma_f32_16x16x32_bf16(A[tc][1], B[tr3 * 3 + tc][1], acc[mt], 0, 0, 0);
      }
    }
  }
  const size_t haloPx = (size_t)b * IMST + (size_t)((R + 1) * 34 + C + 1) * 64;
#pragma unroll
  for (int mt = 0; mt < 4; ++mt) {
    int cob = mt * 16 + quad * 4;
    float v[4];
#pragma unroll
    for (int r = 0; r < 4; ++r) v[r] = acc[mt][r] + biasL[cob + r];
    if (MODE == 0) {
      uint2 pk, pkr;
      pk.x = pk2(v[0], v[1]); pk.y = pk2(v[2], v[3]);
      pkr.x = pk2(fmaxf(v[0], 0.f), fmaxf(v[1], 0.f));
      pkr.y = pk2(fmaxf(v[2], 0.f), fmaxf(v[3], 0.f));
      *(uint2*)&d1[haloPx + cob] = pk;    // n1T (raw, for pool)
      *(uint2*)&d2[haloPx + cob] = pkr;   // n1reluT (for e2 convA)
    } else if (MODE == 1) {
      float ps[4] = {0.f, 0.f, 0.f, 0.f};
      const size_t pb = (size_t)b * IMST + (size_t)(R * 34 + C) * 64 + cob;
#pragma unroll
      for (int dy = 0; dy < 3; ++dy)
#pragma unroll
        for (int dx = 0; dx < 3; ++dx) {
          uint2 u = *(const uint2*)&d2[pb + (size_t)(dy * 34 + dx) * 64];  // d2 = n1T
          ps[0] += bf2f((u16)(u.x & 0xffff));
          ps[1] += bf2f((u16)(u.x >> 16));
          ps[2] += bf2f((u16)(u.y & 0xffff));
          ps[3] += bf2f((u16)(u.y >> 16));
        }
      float rows = 3.f - (R == 0 ? 1.f : 0.f) - (R == 31 ? 1.f : 0.f);
      float cols = 3.f - (C == 0 ? 1.f : 0.f) - (C == 31 ? 1.f : 0.f);
      float inv = 1.f / (rows * cols);
      uint2 pkr;
      float t0 = fmaxf(v[0] + ps[0] * inv * cmL[cob], 0.f);
      float t1 = fmaxf(v[1] + ps[1] * inv * cmL[cob + 1], 0.f);
      float t2 = fmaxf(v[2] + ps[2] * inv * cmL[cob + 2], 0.f);
      float t3 = fmaxf(v[3] + ps[3] * inv * cmL[cob + 3], 0.f);
      pkr.x = pk2(t0, t1); pkr.y = pk2(t2, t3);
      *(uint2*)&d1[haloPx + cob] = pkr;   // n2reluT
    } else if (MODE == 2) {
      size_t base = (size_t)b * 65536 + (size_t)cob * 1024 + R * 32 + C;
#pragma unroll
      for (int r = 0; r < 4; ++r)
        outp[base + (size_t)r * 1024] = v[r] + xin[base + (size_t)r * 1024] * cmL[cob + r];
    } else {
      size_t base = (size_t)b * 65536 + (size_t)cob * 1024 + R * 32 + C;
#pragma unroll
      for (int r = 0; r < 4; ++r)
        outp[base + (size_t)r * 1024] += v[r];
    }
  }
}

extern "C" void kernel_launch(void* const* d_in, const int* in_sizes, int n_in,
                              void* d_out, int out_size, void* d_ws, size_t ws_size,
                              hipStream_t stream) {
  const float* x  = (const float*)d_in[0];
  const float* a1 = (const float*)d_in[1];
  const float* a2 = (const float*)d_in[2];
  const float* W1[4] = {(const float*)d_in[3], (const float*)d_in[5],
                        (const float*)d_in[7], (const float*)d_in[9]};
  const float* W2[4] = {(const float*)d_in[4], (const float*)d_in[6],
                        (const float*)d_in[8], (const float*)d_in[10]};
  float* out = (float*)d_out;
  char* ws = (char*)d_ws;
  const size_t HB = (size_t)IMST * 64 * 2;  // 9,469,952 B per halo buffer
  u16* xT  = (u16*)ws;
  u16* t   = (u16*)(ws + HB);
  u16* n1T = (u16*)(ws + 2 * HB);
  u16* n1r = (u16*)(ws + 3 * HB);
  u16* n2r = (u16*)(ws + 4 * HB);
  char* p = ws + 5 * HB;
  float* st  = (float*)p;            p += 8256 * 4;
  u16* wT1   = (u16*)p;              p += 4 * 36864 * 2;
  u16* wG    = (u16*)p;              p += 4 * 49152 * 2;
  u16* wE    = (u16*)p;              p += 36864 * 2;
  float* pA  = (float*)p;            p += 1024 * 128 * 4;
  float* pC  = (float*)p;            // 1024*1024*4

  hipMemsetAsync(ws, 0, 5 * HB, stream);  // zero halos (+interiors, overwritten)
  pack_wT1_k<<<36, 256, 0, stream>>>(W1[0], W1[1], W1[2], W1[3], wT1);
  pack_wG_k<<<dim3(96, 4), 256, 0, stream>>>(W2[0], W2[1], W2[2], W2[3], wG);
  transpose_k<<<1024, 256, 0, stream>>>(x, xT);

  dim3 gs(16, 64);
  const u16* ins[4] = {xT, xT, n1r, n2r};
  for (int e = 0; e < 4; ++e) {
    convA_k<<<gs, 256, 0, stream>>>(ins[e], wT1 + e * 36864, t, pA);
    reducerA_k<<<64, 256, 0, stream>>>(pA, a1, st);
    renorm_k<<<2048, 256, 0, stream>>>(t, st);
    convC_k<<<gs, 512, 0, stream>>>(t, wG + e * 49152, pC);
    redCprepE_k<<<64, 256, 0, stream>>>(pC, W2[e], a1, a2, st, wE);
    if (e == 0) {
      convE_k<0><<<gs, 256, 0, stream>>>(t, st, wE, nullptr, nullptr, n1T, n1r);
    } else if (e == 1) {
      convE_k<1><<<gs, 256, 0, stream>>>(t, st, wE, nullptr, nullptr, n2r, n1T);
    } else if (e == 2) {
      convE_k<2><<<gs, 256, 0, stream>>>(t, st, wE, out, x, nullptr, nullptr);
    } else {
      convE_k<3><<<gs, 256, 0, stream>>>(t, st, wE, out, nullptr, nullptr, nullptr);
    }
  }
}

// Round 7
// 643.392 us; speedup vs baseline: 1.7212x; 1.1806x over previous
//
#include <hip/hip_runtime.h>

#define EPS 1e-5f
#define NRED 65536.0f   // B*H*W = 64*32*32
#define IMST 73984      // 34*34*64 halo image stride (elements)

typedef short bf16x8 __attribute__((ext_vector_type(8)));
typedef float f32x4 __attribute__((ext_vector_type(4)));
typedef unsigned short u16;

__device__ __forceinline__ u16 f2bf(float x) {  // RNE f32->bf16
  union { float f; unsigned u; } v; v.f = x;
  unsigned r = v.u + 0x7FFF + ((v.u >> 16) & 1);
  return (u16)(r >> 16);
}
__device__ __forceinline__ float bf2f(u16 h) {
  union { unsigned u; float f; } v; v.u = ((unsigned)h) << 16;
  return v.f;
}
__device__ __forceinline__ unsigned pk2(float a, float b) {
  return (unsigned)f2bf(a) | ((unsigned)f2bf(b) << 16);
}

// DPP row-shift reduce over the 16-lane DPP row (ln = lane&15). Sum lands in
// ln==15. Pure VALU — no LDS pipe (r6: convC 83->~50us from this alone).
template <int CTRL>
__device__ __forceinline__ float dpp_mov(float x) {
  int xi = __builtin_bit_cast(int, x);
  int r = __builtin_amdgcn_update_dpp(0, xi, CTRL, 0xF, 0xF, true);
  return __builtin_bit_cast(float, r);
}
__device__ __forceinline__ float row_reduce16(float x) {
  x += dpp_mov<0x111>(x);
  x += dpp_mov<0x112>(x);
  x += dpp_mov<0x114>(x);
  x += dpp_mov<0x118>(x);
  return x;  // valid in ln==15
}

// st layout (floats): [0,64) s1 | [64,128) b1 | [1792,1856) bias2[c] | [8192,8256) cm[c]

__global__ void pack_wT1_k(const float* __restrict__ w0, const float* __restrict__ w1,
                           const float* __restrict__ w2, const float* __restrict__ w3,
                           u16* __restrict__ wT1) {
  int e = blockIdx.x / 9, tap = blockIdx.x % 9;
  const float* w = e == 0 ? w0 : e == 1 ? w1 : e == 2 ? w2 : w3;
  u16* dst = wT1 + e * 36864 + tap * 4096;
  for (int idx = threadIdx.x; idx < 4096; idx += 256) {
    int co = idx >> 6, ci = idx & 63;
    dst[idx] = f2bf(w[(co * 64 + ci) * 9 + tap]);
  }
}

// wG[e][g*12+ch*4+q][co][cig] bf16, zero where tap=ch*4+q > 8
__global__ void pack_wG_k(const float* __restrict__ w0, const float* __restrict__ w1,
                          const float* __restrict__ w2, const float* __restrict__ w3,
                          u16* __restrict__ wG) {
  int e = blockIdx.y;
  const float* w = e == 0 ? w0 : e == 1 ? w1 : e == 2 ? w2 : w3;
  int bx = blockIdx.x;              // g*12 + ch*4 + q
  int q = bx & 3, ch = (bx >> 2) % 3, g = bx / 12;
  int tap = ch * 4 + q;
  u16* dst = wG + e * 49152 + bx * 512;
  for (int idx = threadIdx.x; idx < 512; idx += 256) {
    int co = idx >> 3, cig = idx & 7;
    float v = (tap <= 8) ? w[(co * 64 + g * 8 + cig) * 9 + tap] : 0.f;
    dst[idx] = f2bf(v);
  }
}

// x (NCHW f32) -> xT = bf16(relu(x)) halo pixel-major. grid 1024, block 256.
__global__ __launch_bounds__(256) void transpose_k(const float* __restrict__ x,
                                                   u16* __restrict__ xT) {
  __shared__ __align__(16) u16 sh[64 * 72];
  const int tid = threadIdx.x;
  const int b = blockIdx.x >> 4, slab = blockIdx.x & 15;
  const int ln = tid & 63, w = tid >> 6;
  const float* xb = x + (size_t)b * 65536 + slab * 64;
#pragma unroll
  for (int i = 0; i < 16; ++i) {
    int ci = w + i * 4;
    float v = xb[ci * 1024 + ln];
    sh[ln * 72 + ci] = f2bf(fmaxf(v, 0.f));
  }
  __syncthreads();
  u16* dst = xT + (size_t)b * IMST;
#pragma unroll
  for (int j = 0; j < 2; ++j) {
    int idx = tid + j * 256;
    int p = idx >> 3, oct = idx & 7;
    int gp = slab * 64 + p;
    int R = gp >> 5, C = gp & 31;
    *(uint4*)&dst[((R + 1) * 34 + C + 1) * 64 + oct * 8] = *(const uint4*)&sh[p * 72 + oct * 8];
  }
}

// ---------------- convA: t = conv3x3(xin, W1) + per-block stats partials -----
// block 256 = 4 waves; each wave: 2 row-tiles (NT=2), 64 co. grid (8, 64).
// launch_bounds(...,2): ~256 VGPR budget so the K-step pipeline holds regs.
__global__ __launch_bounds__(256, 2) void convA_k(const u16* __restrict__ xin,
                                                  const u16* __restrict__ wT,
                                                  u16* __restrict__ t,
                                                  float* __restrict__ pA) {
  __shared__ float sA[64], qA[64];
  const int tid = threadIdx.x;
  const int b = blockIdx.y;
  if (tid < 64) { sA[tid] = 0.f; qA[tid] = 0.f; }
  __syncthreads();
  const int lane = tid & 63, w = tid >> 6;
  const int ln = lane & 15, quad = lane >> 4;
  const int R0 = blockIdx.x * 4 + (w >> 1) * 2;
  const int C = (w & 1) * 16 + ln;
  size_t baseB[2];
#pragma unroll
  for (int nt = 0; nt < 2; ++nt)
    baseB[nt] = (size_t)b * IMST + (size_t)((R0 + nt) * 34 + C) * 64 + quad * 8;
  f32x4 acc[4][2];
#pragma unroll
  for (int mt = 0; mt < 4; ++mt)
#pragma unroll
    for (int nt = 0; nt < 2; ++nt) acc[mt][nt] = (f32x4){0.f, 0.f, 0.f, 0.f};
#pragma unroll
  for (int tap = 0; tap < 9; ++tap) {
    const size_t toff = (size_t)((tap / 3) * 34 + tap % 3) * 64;
#pragma unroll
    for (int half = 0; half < 2; ++half) {
      bf16x8 b0 = *(const bf16x8*)&xin[baseB[0] + toff + half * 32];
      bf16x8 b1 = *(const bf16x8*)&xin[baseB[1] + toff + half * 32];
#pragma unroll
      for (int mt = 0; mt < 4; ++mt) {
        bf16x8 aw = *(const bf16x8*)&wT[(size_t)((tap * 64 + mt * 16 + ln) * 64) + half * 32 + quad * 8];
        acc[mt][0] = __builtin_amdgcn_mfma_f32_16x16x32_bf16(aw, b0, acc[mt][0], 0, 0, 0);
        acc[mt][1] = __builtin_amdgcn_mfma_f32_16x16x32_bf16(aw, b1, acc[mt][1], 0, 0, 0);
      }
    }
  }
#pragma unroll
  for (int nt = 0; nt < 2; ++nt) {
    u16* tb = t + (size_t)b * IMST + (size_t)((R0 + nt + 1) * 34 + C + 1) * 64;
#pragma unroll
    for (int mt = 0; mt < 4; ++mt) {
      uint2 pk;
      pk.x = pk2(acc[mt][nt][0], acc[mt][nt][1]);
      pk.y = pk2(acc[mt][nt][2], acc[mt][nt][3]);
      *(uint2*)&tb[mt * 16 + quad * 4] = pk;
#pragma unroll
      for (int r = 0; r < 4; ++r) {
        float v = acc[mt][nt][r];
        float s = row_reduce16(v);
        float q = row_reduce16(v * v);
        if (ln == 15) {
          atomicAdd(&sA[mt * 16 + quad * 4 + r], s);
          atomicAdd(&qA[mt * 16 + quad * 4 + r], q);
        }
      }
    }
  }
  __syncthreads();
  const int blk = blockIdx.y * 8 + blockIdx.x;
  if (tid < 64) pA[blk * 128 + tid] = sA[tid];
  else if (tid < 128) pA[blk * 128 + tid] = qA[tid - 64];
}

// reducerA: grid(64); block c reduces pA[*][c] / pA[*][64+c]
__global__ __launch_bounds__(256) void reducerA_k(const float* __restrict__ pA,
                                                  const float* __restrict__ a1,
                                                  float* __restrict__ st) {
  const int tid = threadIdx.x, c = blockIdx.x;
  float s = 0.f, q = 0.f;
  for (int i = tid; i < 512; i += 256) {
    s += pA[i * 128 + c];
    q += pA[i * 128 + 64 + c];
  }
#pragma unroll
  for (int off = 32; off; off >>= 1) { s += __shfl_xor(s, off); q += __shfl_xor(q, off); }
  __shared__ float red[8];
  int wv = tid >> 6;
  if ((tid & 63) == 0) { red[wv] = s; red[4 + wv] = q; }
  __syncthreads();
  if (tid == 0) {
    float S = red[0] + red[1] + red[2] + red[3];
    float Q = red[4] + red[5] + red[6] + red[7];
    int g = c >> 3;
    float m = 0.f;
    for (int i = g; i < 8; ++i) m += a1[i];
    float mu = S * (1.f / NRED);
    float var = Q * (1.f / NRED) - mu * mu;
    float r = rsqrtf(var + EPS);
    st[c] = r * m;
    st[64 + c] = -mu * r * m;
  }
}

// renorm: t := bf16(t*s1[ci] + b1[ci]) interior only. grid 2048, block 256.
__global__ __launch_bounds__(256) void renorm_k(u16* __restrict__ t,
                                                const float* __restrict__ st) {
  __shared__ float s1L[64], b1L[64];
  int tid = threadIdx.x;
  if (tid < 64) { s1L[tid] = st[tid]; b1L[tid] = st[64 + tid]; }
  __syncthreads();
  int idx = blockIdx.x * 256 + tid;
  int b = idx >> 13, rem = idx & 8191;
  int p = rem >> 3, oct = rem & 7;
  int R = p >> 5, C = p & 31;
  u16* ptr = t + (size_t)b * IMST + (size_t)((R + 1) * 34 + C + 1) * 64 + oct * 8;
  uint4 u = *(const uint4*)ptr;
  unsigned vals[4] = {u.x, u.y, u.z, u.w};
  uint4 o;
  unsigned res[4];
#pragma unroll
  for (int i = 0; i < 4; ++i) {
    int ci = oct * 8 + i * 2;
    float lo = bf2f((u16)(vals[i] & 0xffff)) * s1L[ci] + b1L[ci];
    float hi = bf2f((u16)(vals[i] >> 16)) * s1L[ci + 1] + b1L[ci + 1];
    res[i] = pk2(lo, hi);
  }
  o.x = res[0]; o.y = res[1]; o.z = res[2]; o.w = res[3];
  *(uint4*)ptr = o;
}

// ---------------- convC: per-group prefix stats of conv2 ---------------------
// block 512 = 8 waves (nt = w&3 pxtile, ch2 = w>>2 co-half); grid (16, 64).
__global__ __launch_bounds__(512, 2) void convC_k(const u16* __restrict__ t,
                                                  const u16* __restrict__ wG,
                                                  float* __restrict__ pC) {
  __shared__ float sC[512], qC[512];
  const int tid = threadIdx.x;
  const int b = blockIdx.y;
  sC[tid] = 0.f; qC[tid] = 0.f;
  __syncthreads();
  const int lane = tid & 63, w = tid >> 6;
  const int ln = lane & 15, quad = lane >> 4;
  const int nt = w & 3, ch2 = w >> 2;
  const int R = blockIdx.x * 2 + (nt >> 1);
  const int C = (nt & 1) * 16 + ln;
  const size_t baseB = (size_t)b * IMST + (size_t)(R * 34 + C) * 64;
  size_t po[3];
#pragma unroll
  for (int ch = 0; ch < 3; ++ch) {
    int tp = ch * 4 + quad; if (tp > 8) tp = 8;  // A is zero there
    po[ch] = baseB + (size_t)((tp / 3) * 34 + tp % 3) * 64;
  }
  bf16x8 B[3][8];
#pragma unroll
  for (int ch = 0; ch < 3; ++ch)
#pragma unroll
    for (int g = 0; g < 8; ++g)
      B[ch][g] = *(const bf16x8*)&t[po[ch] + g * 8];
  f32x4 acc[8][2];
#pragma unroll
  for (int g = 0; g < 8; ++g)
#pragma unroll
    for (int m = 0; m < 2; ++m) acc[g][m] = (f32x4){0.f, 0.f, 0.f, 0.f};
#pragma unroll
  for (int g = 0; g < 8; ++g) {
    bf16x8 A[3][2];
#pragma unroll
    for (int ch = 0; ch < 3; ++ch)
#pragma unroll
      for (int mtl = 0; mtl < 2; ++mtl)
        A[ch][mtl] = *(const bf16x8*)&wG[((g * 12 + ch * 4 + quad) * 64 + ch2 * 32 + mtl * 16 + ln) * 8];
#pragma unroll
    for (int ch = 0; ch < 3; ++ch)
#pragma unroll
      for (int mtl = 0; mtl < 2; ++mtl)
        acc[g][mtl] = __builtin_amdgcn_mfma_f32_16x16x32_bf16(A[ch][mtl], B[ch][g], acc[g][mtl], 0, 0, 0);
  }
  f32x4 P[2];
  P[0] = (f32x4){0.f, 0.f, 0.f, 0.f};
  P[1] = (f32x4){0.f, 0.f, 0.f, 0.f};
#pragma unroll
  for (int k = 0; k < 8; ++k) {
    P[0] += acc[k][0]; P[1] += acc[k][1];
#pragma unroll
    for (int mtl = 0; mtl < 2; ++mtl) {
#pragma unroll
      for (int r = 0; r < 4; ++r) {
        float v = P[mtl][r];
        float s = row_reduce16(v);
        float q = row_reduce16(v * v);
        if (ln == 15) {
          int co = ch2 * 32 + mtl * 16 + quad * 4 + r;
          atomicAdd(&sC[k * 64 + co], s);
          atomicAdd(&qC[k * 64 + co], q);
        }
      }
    }
  }
  __syncthreads();
  const int blk = blockIdx.y * 16 + blockIdx.x;
  pC[blk * 1024 + tid] = sC[tid];
  pC[blk * 1024 + 512 + tid] = qC[tid];
}

// redCprepE: grid(64) block c: reduce per-(k,c) stats, finalizeC + fold g
// into wE[tap][co=c][ci]; bias2 -> st[1792+c], cm -> st[8192+c].
__global__ __launch_bounds__(256) void redCprepE_k(const float* __restrict__ pC,
                                                   const float* __restrict__ w2,
                                                   const float* __restrict__ a1,
                                                   const float* __restrict__ a2,
                                                   float* __restrict__ st,
                                                   u16* __restrict__ wE) {
  const int tid = threadIdx.x, c = blockIdx.x;
  float s[8], q[8];
#pragma unroll
  for (int k = 0; k < 8; ++k) { s[k] = 0.f; q[k] = 0.f; }
  for (int i = tid; i < 1024; i += 256) {
#pragma unroll
    for (int k = 0; k < 8; ++k) {
      s[k] += pC[i * 1024 + k * 64 + c];
      q[k] += pC[i * 1024 + 512 + k * 64 + c];
    }
  }
#pragma unroll
  for (int k = 0; k < 8; ++k) {
#pragma unroll
    for (int off = 32; off; off >>= 1) { s[k] += __shfl_xor(s[k], off); q[k] += __shfl_xor(q[k], off); }
  }
  __shared__ float red[4][16];
  __shared__ float gL[8];
  int wv = tid >> 6;
  if ((tid & 63) == 0) {
#pragma unroll
    for (int k = 0; k < 8; ++k) { red[wv][k * 2] = s[k]; red[wv][k * 2 + 1] = q[k]; }
  }
  __syncthreads();
  if (tid == 0) {
    float suf = 0.f, bias = 0.f;
    for (int k = 7; k >= 0; --k) {
      float S = red[0][k * 2] + red[1][k * 2] + red[2][k * 2] + red[3][k * 2];
      float Q = red[0][k * 2 + 1] + red[1][k * 2 + 1] + red[2][k * 2 + 1] + red[3][k * 2 + 1];
      float mu = S * (1.f / NRED);
      float var = Q * (1.f / NRED) - mu * mu;
      float rr = rsqrtf(var + EPS);
      bias -= a2[k] * mu * rr;
      suf += a2[k] * rr;
      gL[k] = suf;
    }
    st[1792 + c] = bias;
    int g = c >> 3;
    float m1 = 0.f, m2 = 0.f;
    for (int i = g; i < 8; ++i) { m1 += a1[i]; m2 += a2[i]; }
    st[8192 + c] = m1 * m2;
  }
  __syncthreads();
  for (int idx = tid; idx < 576; idx += 256) {
    int tap = idx >> 6, ci = idx & 63;
    wE[(tap * 64 + c) * 64 + ci] = f2bf(w2[(c * 64 + ci) * 9 + tap] * gL[ci >> 3]);
  }
}

// ---------------- convE: mixed conv2 + fused epilogue ------------------------
// block 256 = 4 waves, NT=2 row-tiles per wave; grid (8, 64).
// MODE 0: n1T/n1reluT | 1: n2reluT = relu(v + pool(n1T)*cm) | 2: out = v + x*cm | 3: out += v
template <int MODE>
__global__ __launch_bounds__(256, 2) void convE_k(const u16* __restrict__ t,
                                                  const float* __restrict__ st,
                                                  const u16* __restrict__ wE,
                                                  float* __restrict__ outp,
                                                  const float* __restrict__ xin,
                                                  u16* __restrict__ d1,
                                                  u16* __restrict__ d2) {
  __shared__ float cmL[64], biasL[64];
  const int tid = threadIdx.x;
  const int b = blockIdx.y;
  if (tid < 64) { cmL[tid] = st[8192 + tid]; biasL[tid] = st[1792 + tid]; }
  __syncthreads();
  const int lane = tid & 63, w = tid >> 6;
  const int ln = lane & 15, quad = lane >> 4;
  const int R0 = blockIdx.x * 4 + (w >> 1) * 2;
  const int C = (w & 1) * 16 + ln;
  size_t baseB[2];
#pragma unroll
  for (int nt = 0; nt < 2; ++nt)
    baseB[nt] = (size_t)b * IMST + (size_t)((R0 + nt) * 34 + C) * 64 + quad * 8;
  f32x4 acc[4][2];
#pragma unroll
  for (int mt = 0; mt < 4; ++mt)
#pragma unroll
    for (int nt = 0; nt < 2; ++nt) acc[mt][nt] = (f32x4){0.f, 0.f, 0.f, 0.f};
#pragma unroll
  for (int tap = 0; tap < 9; ++tap) {
    const size_t toff = (size_t)((tap / 3) * 34 + tap % 3) * 64;
#pragma unroll
    for (int half = 0; half < 2; ++half) {
      bf16x8 b0 = *(const bf16x8*)&t[baseB[0] + toff + half * 32];
      bf16x8 b1 = *(const bf16x8*)&t[baseB[1] + toff + half * 32];
#pragma unroll
      for (int mt = 0; mt < 4; ++mt) {
        bf16x8 aw = *(const bf16x8*)&wE[(size_t)((tap * 64 + mt * 16 + ln) * 64) + half * 32 + quad * 8];
        acc[mt][0] = __builtin_amdgcn_mfma_f32_16x16x32_bf16(aw, b0, acc[mt][0], 0, 0, 0);
        acc[mt][1] = __builtin_amdgcn_mfma_f32_16x16x32_bf16(aw, b1, acc[mt][1], 0, 0, 0);
      }
    }
  }
#pragma unroll
  for (int nt = 0; nt < 2; ++nt) {
    const int R = R0 + nt;
    const size_t haloPx = (size_t)b * IMST + (size_t)((R + 1) * 34 + C + 1) * 64;
#pragma unroll
    for (int mt = 0; mt < 4; ++mt) {
      int cob = mt * 16 + quad * 4;
      float v[4];
#pragma unroll
      for (int r = 0; r < 4; ++r) v[r] = acc[mt][nt][r] + biasL[cob + r];
      if (MODE == 0) {
        uint2 pk, pkr;
        pk.x = pk2(v[0], v[1]); pk.y = pk2(v[2], v[3]);
        pkr.x = pk2(fmaxf(v[0], 0.f), fmaxf(v[1], 0.f));
        pkr.y = pk2(fmaxf(v[2], 0.f), fmaxf(v[3], 0.f));
        *(uint2*)&d1[haloPx + cob] = pk;    // n1T (raw, for pool)
        *(uint2*)&d2[haloPx + cob] = pkr;   // n1reluT (for e2 convA)
      } else if (MODE == 1) {
        float ps[4] = {0.f, 0.f, 0.f, 0.f};
        const size_t pb = (size_t)b * IMST + (size_t)(R * 34 + C) * 64 + cob;
#pragma unroll
        for (int dy = 0; dy < 3; ++dy)
#pragma unroll
          for (int dx = 0; dx < 3; ++dx) {
            uint2 u = *(const uint2*)&d2[pb + (size_t)(dy * 34 + dx) * 64];  // d2 = n1T
            ps[0] += bf2f((u16)(u.x & 0xffff));
            ps[1] += bf2f((u16)(u.x >> 16));
            ps[2] += bf2f((u16)(u.y & 0xffff));
            ps[3] += bf2f((u16)(u.y >> 16));
          }
        float rows = 3.f - (R == 0 ? 1.f : 0.f) - (R == 31 ? 1.f : 0.f);
        float cols = 3.f - (C == 0 ? 1.f : 0.f) - (C == 31 ? 1.f : 0.f);
        float inv = 1.f / (rows * cols);
        uint2 pkr;
        float t0 = fmaxf(v[0] + ps[0] * inv * cmL[cob], 0.f);
        float t1 = fmaxf(v[1] + ps[1] * inv * cmL[cob + 1], 0.f);
        float t2 = fmaxf(v[2] + ps[2] * inv * cmL[cob + 2], 0.f);
        float t3 = fmaxf(v[3] + ps[3] * inv * cmL[cob + 3], 0.f);
        pkr.x = pk2(t0, t1); pkr.y = pk2(t2, t3);
        *(uint2*)&d1[haloPx + cob] = pkr;   // n2reluT
      } else if (MODE == 2) {
        size_t base = (size_t)b * 65536 + (size_t)cob * 1024 + R * 32 + C;
#pragma unroll
        for (int r = 0; r < 4; ++r)
          outp[base + (size_t)r * 1024] = v[r] + xin[base + (size_t)r * 1024] * cmL[cob + r];
      } else {
        size_t base = (size_t)b * 65536 + (size_t)cob * 1024 + R * 32 + C;
#pragma unroll
        for (int r = 0; r < 4; ++r)
          outp[base + (size_t)r * 1024] += v[r];
      }
    }
  }
}

extern "C" void kernel_launch(void* const* d_in, const int* in_sizes, int n_in,
                              void* d_out, int out_size, void* d_ws, size_t ws_size,
                              hipStream_t stream) {
  const float* x  = (const float*)d_in[0];
  const float* a1 = (const float*)d_in[1];
  const float* a2 = (const float*)d_in[2];
  const float* W1[4] = {(const float*)d_in[3], (const float*)d_in[5],
                        (const float*)d_in[7], (const float*)d_in[9]};
  const float* W2[4] = {(const float*)d_in[4], (const float*)d_in[6],
                        (const float*)d_in[8], (const float*)d_in[10]};
  float* out = (float*)d_out;
  char* ws = (char*)d_ws;
  const size_t HB = (size_t)IMST * 64 * 2;  // 9,469,952 B per halo buffer
  u16* xT  = (u16*)ws;
  u16* t   = (u16*)(ws + HB);
  u16* n1T = (u16*)(ws + 2 * HB);
  u16* n1r = (u16*)(ws + 3 * HB);
  u16* n2r = (u16*)(ws + 4 * HB);
  char* p = ws + 5 * HB;
  float* st  = (float*)p;            p += 8256 * 4;
  u16* wT1   = (u16*)p;              p += 4 * 36864 * 2;
  u16* wG    = (u16*)p;              p += 4 * 49152 * 2;
  u16* wE    = (u16*)p;              p += 36864 * 2;
  float* pA  = (float*)p;            p += 1024 * 128 * 4;
  float* pC  = (float*)p;            // 1024*1024*4

  hipMemsetAsync(ws, 0, 5 * HB, stream);  // zero halos (+interiors, overwritten)
  pack_wT1_k<<<36, 256, 0, stream>>>(W1[0], W1[1], W1[2], W1[3], wT1);
  pack_wG_k<<<dim3(96, 4), 256, 0, stream>>>(W2[0], W2[1], W2[2], W2[3], wG);
  transpose_k<<<1024, 256, 0, stream>>>(x, xT);

  dim3 gAE(8, 64), gC(16, 64);
  const u16* ins[4] = {xT, xT, n1r, n2r};
  for (int e = 0; e < 4; ++e) {
    convA_k<<<gAE, 256, 0, stream>>>(ins[e], wT1 + e * 36864, t, pA);
    reducerA_k<<<64, 256, 0, stream>>>(pA, a1, st);
    renorm_k<<<2048, 256, 0, stream>>>(t, st);
    convC_k<<<gC, 512, 0, stream>>>(t, wG + e * 49152, pC);
    redCprepE_k<<<64, 256, 0, stream>>>(pC, W2[e], a1, a2, st, wE);
    if (e == 0) {
      convE_k<0><<<gAE, 256, 0, stream>>>(t, st, wE, nullptr, nullptr, n1T, n1r);
    } else if (e == 1) {
      convE_k<1><<<gAE, 256, 0, stream>>>(t, st, wE, nullptr, nullptr, n2r, n1T);
    } else if (e == 2) {
      convE_k<2><<<gAE, 256, 0, stream>>>(t, st, wE, out, x, nullptr, nullptr);
    } else {
      convE_k<3><<<gAE, 256, 0, stream>>>(t, st, wE, out, nullptr, nullptr, nullptr);
    }
  }
}

// Round 8
// 550.448 us; speedup vs baseline: 2.0119x; 1.1688x over previous
//
#include <hip/hip_runtime.h>

#define EPS 1e-5f
#define NRED 65536.0f   // B*H*W = 64*32*32
#define IMST 73984      // 34*34*64 halo image stride (elements)

typedef short bf16x8 __attribute__((ext_vector_type(8)));
typedef float f32x4 __attribute__((ext_vector_type(4)));
typedef unsigned short u16;

#define MFMA16(a, b, c) __builtin_amdgcn_mfma_f32_16x16x32_bf16(a, b, c, 0, 0, 0)

__device__ __forceinline__ u16 f2bf(float x) {  // RNE f32->bf16
  union { float f; unsigned u; } v; v.f = x;
  unsigned r = v.u + 0x7FFF + ((v.u >> 16) & 1);
  return (u16)(r >> 16);
}
__device__ __forceinline__ float bf2f(u16 h) {
  union { unsigned u; float f; } v; v.u = ((unsigned)h) << 16;
  return v.f;
}
__device__ __forceinline__ unsigned pk2(float a, float b) {
  return (unsigned)f2bf(a) | ((unsigned)f2bf(b) << 16);
}

// DPP row-shift reduce over 16-lane rows; sum valid in ln==15. Pure VALU.
template <int CTRL>
__device__ __forceinline__ float dpp_mov(float x) {
  int xi = __builtin_bit_cast(int, x);
  int r = __builtin_amdgcn_update_dpp(0, xi, CTRL, 0xF, 0xF, true);
  return __builtin_bit_cast(float, r);
}
__device__ __forceinline__ float row_reduce16(float x) {
  x += dpp_mov<0x111>(x);
  x += dpp_mov<0x112>(x);
  x += dpp_mov<0x114>(x);
  x += dpp_mov<0x118>(x);
  return x;
}

// Stage a 4-row x 34-col x 64-ci halo patch (8704 elems) from global into LDS
// with pixel stride padded 64->80 elems (160 B, 16B-aligned). All loads are
// independent -> compiler pipelines them (unlike MFMA-consumed loads).
__device__ __forceinline__ void stage_patch(const u16* __restrict__ src,
                                            u16* __restrict__ shp, int tid) {
#pragma unroll
  for (int i = 0; i < 4; ++i) {
    int c = i * 256 + tid;              // 16B chunk id
    int px = c >> 3, oct = c & 7;
    *(uint4*)&shp[px * 80 + oct * 8] = *(const uint4*)&src[c * 8];
  }
  if (tid < 64) {
    int c = 1024 + tid;
    int px = c >> 3, oct = c & 7;
    *(uint4*)&shp[px * 80 + oct * 8] = *(const uint4*)&src[c * 8];
  }
}

// st layout (floats): [0,64) s1 | [64,128) b1 | [1792,1856) bias2[c] | [8192,8256) cm[c]

__global__ void pack_wT1_k(const float* __restrict__ w0, const float* __restrict__ w1,
                           const float* __restrict__ w2, const float* __restrict__ w3,
                           u16* __restrict__ wT1) {
  int e = blockIdx.x / 9, tap = blockIdx.x % 9;
  const float* w = e == 0 ? w0 : e == 1 ? w1 : e == 2 ? w2 : w3;
  u16* dst = wT1 + e * 36864 + tap * 4096;
  for (int idx = threadIdx.x; idx < 4096; idx += 256) {
    int co = idx >> 6, ci = idx & 63;
    dst[idx] = f2bf(w[(co * 64 + ci) * 9 + tap]);
  }
}

// wG[e][g*12+ch*4+q][co][cig] bf16, zero where tap=ch*4+q > 8
__global__ void pack_wG_k(const float* __restrict__ w0, const float* __restrict__ w1,
                          const float* __restrict__ w2, const float* __restrict__ w3,
                          u16* __restrict__ wG) {
  int e = blockIdx.y;
  const float* w = e == 0 ? w0 : e == 1 ? w1 : e == 2 ? w2 : w3;
  int bx = blockIdx.x;              // g*12 + ch*4 + q
  int q = bx & 3, ch = (bx >> 2) % 3, g = bx / 12;
  int tap = ch * 4 + q;
  u16* dst = wG + e * 49152 + bx * 512;
  for (int idx = threadIdx.x; idx < 512; idx += 256) {
    int co = idx >> 3, cig = idx & 7;
    float v = (tap <= 8) ? w[(co * 64 + g * 8 + cig) * 9 + tap] : 0.f;
    dst[idx] = f2bf(v);
  }
}

// x (NCHW f32) -> xT = bf16(relu(x)) halo pixel-major. grid 1024, block 256.
__global__ __launch_bounds__(256) void transpose_k(const float* __restrict__ x,
                                                   u16* __restrict__ xT) {
  __shared__ __align__(16) u16 sh[64 * 72];
  const int tid = threadIdx.x;
  const int b = blockIdx.x >> 4, slab = blockIdx.x & 15;
  const int ln = tid & 63, w = tid >> 6;
  const float* xb = x + (size_t)b * 65536 + slab * 64;
#pragma unroll
  for (int i = 0; i < 16; ++i) {
    int ci = w + i * 4;
    float v = xb[ci * 1024 + ln];
    sh[ln * 72 + ci] = f2bf(fmaxf(v, 0.f));
  }
  __syncthreads();
  u16* dst = xT + (size_t)b * IMST;
#pragma unroll
  for (int j = 0; j < 2; ++j) {
    int idx = tid + j * 256;
    int p = idx >> 3, oct = idx & 7;
    int gp = slab * 64 + p;
    int R = gp >> 5, C = gp & 31;
    *(uint4*)&dst[((R + 1) * 34 + C + 1) * 64 + oct * 8] = *(const uint4*)&sh[p * 72 + oct * 8];
  }
}

// ---------------- convA: t = conv3x3(xin, W1) + per-block stats partials -----
// block 256 = 4 waves: wave w -> (lr = w>>1 row, mh = w&1 co-half). Block tile
// = 2 rows x 32 cols x 64 co. grid (16, 64). B from LDS patch; A pinned in
// VGPRs (loaded before the barrier); loop has ZERO global loads.
__global__ __launch_bounds__(256, 2) void convA_k(const u16* __restrict__ xin,
                                                  const u16* __restrict__ wT,
                                                  u16* __restrict__ t,
                                                  float* __restrict__ pA) {
  __shared__ __align__(16) u16 shp[136 * 80];
  __shared__ float sA[64], qA[64];
  const int tid = threadIdx.x;
  const int b = blockIdx.y, R0 = blockIdx.x * 2;
  if (tid < 64) { sA[tid] = 0.f; qA[tid] = 0.f; }
  stage_patch(xin + (size_t)b * IMST + (size_t)R0 * 2176, shp, tid);
  const int lane = tid & 63, w = tid >> 6;
  const int ln = lane & 15, quad = lane >> 4;
  const int lr = w >> 1, mh = w & 1;
  bf16x8 A[9][2][2];
#pragma unroll
  for (int tap = 0; tap < 9; ++tap)
#pragma unroll
    for (int m2 = 0; m2 < 2; ++m2)
#pragma unroll
      for (int h = 0; h < 2; ++h)
        A[tap][m2][h] = *(const bf16x8*)&wT[(size_t)((tap * 64 + (mh * 2 + m2) * 16 + ln) * 64) + h * 32 + quad * 8];
  __syncthreads();
  f32x4 acc[2][2];  // [m2][nf]
#pragma unroll
  for (int m2 = 0; m2 < 2; ++m2)
#pragma unroll
    for (int nf = 0; nf < 2; ++nf) acc[m2][nf] = (f32x4){0.f, 0.f, 0.f, 0.f};
#pragma unroll
  for (int tap = 0; tap < 9; ++tap) {
    const int dy = tap / 3, dx = tap % 3;
    const int pb = ((lr + dy) * 34 + ln + dx) * 80 + quad * 8;
#pragma unroll
    for (int h = 0; h < 2; ++h) {
      bf16x8 b0 = *(const bf16x8*)&shp[pb + h * 32];
      bf16x8 b1 = *(const bf16x8*)&shp[pb + 16 * 80 + h * 32];
      acc[0][0] = MFMA16(A[tap][0][h], b0, acc[0][0]);
      acc[0][1] = MFMA16(A[tap][0][h], b1, acc[0][1]);
      acc[1][0] = MFMA16(A[tap][1][h], b0, acc[1][0]);
      acc[1][1] = MFMA16(A[tap][1][h], b1, acc[1][1]);
    }
  }
  const int R = R0 + lr;
#pragma unroll
  for (int m2 = 0; m2 < 2; ++m2) {
    const int cob = (mh * 2 + m2) * 16 + quad * 4;
#pragma unroll
    for (int nf = 0; nf < 2; ++nf) {
      u16* tb = t + (size_t)b * IMST + (size_t)((R + 1) * 34 + nf * 16 + ln + 1) * 64 + cob;
      uint2 pk;
      pk.x = pk2(acc[m2][nf][0], acc[m2][nf][1]);
      pk.y = pk2(acc[m2][nf][2], acc[m2][nf][3]);
      *(uint2*)tb = pk;
    }
#pragma unroll
    for (int r = 0; r < 4; ++r) {
      float v0 = acc[m2][0][r], v1 = acc[m2][1][r];
      float s = row_reduce16(v0) + row_reduce16(v1);
      float q = row_reduce16(v0 * v0) + row_reduce16(v1 * v1);
      if (ln == 15) {
        atomicAdd(&sA[cob + r], s);
        atomicAdd(&qA[cob + r], q);
      }
    }
  }
  __syncthreads();
  const int blk = blockIdx.y * 16 + blockIdx.x;
  if (tid < 64) pA[blk * 128 + tid] = sA[tid];
  else if (tid < 128) pA[blk * 128 + tid] = qA[tid - 64];
}

// reducerA: grid(64); block c reduces pA[*][c] / pA[*][64+c]
__global__ __launch_bounds__(256) void reducerA_k(const float* __restrict__ pA,
                                                  const float* __restrict__ a1,
                                                  float* __restrict__ st) {
  const int tid = threadIdx.x, c = blockIdx.x;
  float s = 0.f, q = 0.f;
  for (int i = tid; i < 1024; i += 256) {
    s += pA[i * 128 + c];
    q += pA[i * 128 + 64 + c];
  }
#pragma unroll
  for (int off = 32; off; off >>= 1) { s += __shfl_xor(s, off); q += __shfl_xor(q, off); }
  __shared__ float red[8];
  int wv = tid >> 6;
  if ((tid & 63) == 0) { red[wv] = s; red[4 + wv] = q; }
  __syncthreads();
  if (tid == 0) {
    float S = red[0] + red[1] + red[2] + red[3];
    float Q = red[4] + red[5] + red[6] + red[7];
    int g = c >> 3;
    float m = 0.f;
    for (int i = g; i < 8; ++i) m += a1[i];
    float mu = S * (1.f / NRED);
    float var = Q * (1.f / NRED) - mu * mu;
    float r = rsqrtf(var + EPS);
    st[c] = r * m;
    st[64 + c] = -mu * r * m;
  }
}

// renorm: t := bf16(t*s1[ci] + b1[ci]) interior only. grid 2048, block 256.
__global__ __launch_bounds__(256) void renorm_k(u16* __restrict__ t,
                                                const float* __restrict__ st) {
  __shared__ float s1L[64], b1L[64];
  int tid = threadIdx.x;
  if (tid < 64) { s1L[tid] = st[tid]; b1L[tid] = st[64 + tid]; }
  __syncthreads();
  int idx = blockIdx.x * 256 + tid;
  int b = idx >> 13, rem = idx & 8191;
  int p = rem >> 3, oct = rem & 7;
  int R = p >> 5, C = p & 31;
  u16* ptr = t + (size_t)b * IMST + (size_t)((R + 1) * 34 + C + 1) * 64 + oct * 8;
  uint4 u = *(const uint4*)ptr;
  unsigned vals[4] = {u.x, u.y, u.z, u.w};
  uint4 o;
  unsigned res[4];
#pragma unroll
  for (int i = 0; i < 4; ++i) {
    int ci = oct * 8 + i * 2;
    float lo = bf2f((u16)(vals[i] & 0xffff)) * s1L[ci] + b1L[ci];
    float hi = bf2f((u16)(vals[i] >> 16)) * s1L[ci + 1] + b1L[ci + 1];
    res[i] = pk2(lo, hi);
  }
  o.x = res[0]; o.y = res[1]; o.z = res[2]; o.w = res[3];
  *(uint4*)ptr = o;
}

// ---------------- convC: per-group prefix stats of conv2 ---------------------
// block 256 = 4 waves (nt = w: px-tile), co-half = blockIdx.z. grid (16,64,2).
// Patch AND wG co-half slice staged to LDS; loop is 100% LDS-fed.
__global__ __launch_bounds__(256, 2) void convC_k(const u16* __restrict__ t,
                                                  const u16* __restrict__ wG,
                                                  float* __restrict__ pC) {
  __shared__ __align__(16) u16 shp[136 * 80];      // 21760 B
  __shared__ __align__(16) u16 shA[96 * 32 * 8];   // 49152 B
  __shared__ float sC[256], qC[256];
  const int tid = threadIdx.x;
  const int b = blockIdx.y, R0 = blockIdx.x * 2, ch2 = blockIdx.z;
  sC[tid] = 0.f; qC[tid] = 0.f;
  stage_patch(t + (size_t)b * IMST + (size_t)R0 * 2176, shp, tid);
  // stage wG slice: 96 rows x (32 co-half x 8 cig); 3072 chunks of 16 B
#pragma unroll
  for (int i = 0; i < 12; ++i) {
    int c = i * 256 + tid;
    int bx = c >> 5, lco = c & 31;
    *(uint4*)&shA[c * 8] = *(const uint4*)&wG[(size_t)(bx * 64 + ch2 * 32 + lco) * 8];
  }
  __syncthreads();
  const int lane = tid & 63, w = tid >> 6;
  const int ln = lane & 15, quad = lane >> 4;
  const int lrow = w >> 1, colbase = (w & 1) * 16;
  int pxo[3];
#pragma unroll
  for (int ch = 0; ch < 3; ++ch) {
    int tp = ch * 4 + quad; if (tp > 8) tp = 8;  // A is zero there
    pxo[ch] = ((lrow + tp / 3) * 34 + colbase + ln + tp % 3) * 80;
  }
  f32x4 acc[8][2];
#pragma unroll
  for (int g = 0; g < 8; ++g)
#pragma unroll
    for (int m = 0; m < 2; ++m) acc[g][m] = (f32x4){0.f, 0.f, 0.f, 0.f};
#pragma unroll
  for (int g = 0; g < 8; ++g) {
#pragma unroll
    for (int ch = 0; ch < 3; ++ch) {
      bf16x8 bx = *(const bf16x8*)&shp[pxo[ch] + g * 8];
#pragma unroll
      for (int mtl = 0; mtl < 2; ++mtl) {
        bf16x8 aw = *(const bf16x8*)&shA[((g * 12 + ch * 4 + quad) * 32 + mtl * 16 + ln) * 8];
        acc[g][mtl] = MFMA16(aw, bx, acc[g][mtl]);
      }
    }
  }
  f32x4 P[2];
  P[0] = (f32x4){0.f, 0.f, 0.f, 0.f};
  P[1] = (f32x4){0.f, 0.f, 0.f, 0.f};
#pragma unroll
  for (int k = 0; k < 8; ++k) {
    P[0] += acc[k][0]; P[1] += acc[k][1];
#pragma unroll
    for (int mtl = 0; mtl < 2; ++mtl) {
#pragma unroll
      for (int r = 0; r < 4; ++r) {
        float v = P[mtl][r];
        float s = row_reduce16(v);
        float q = row_reduce16(v * v);
        if (ln == 15) {
          int lco = mtl * 16 + quad * 4 + r;
          atomicAdd(&sC[k * 32 + lco], s);
          atomicAdd(&qC[k * 32 + lco], q);
        }
      }
    }
  }
  __syncthreads();
  const int blk = blockIdx.y * 16 + blockIdx.x;
  const int k = tid >> 5, lco = tid & 31;
  pC[blk * 1024 + k * 64 + ch2 * 32 + lco] = sC[tid];
  pC[blk * 1024 + 512 + k * 64 + ch2 * 32 + lco] = qC[tid];
}

// redCprepE: grid(64) block c: reduce per-(k,c) stats, finalizeC + fold g
// into wE[tap][co=c][ci]; bias2 -> st[1792+c], cm -> st[8192+c].
__global__ __launch_bounds__(256) void redCprepE_k(const float* __restrict__ pC,
                                                   const float* __restrict__ w2,
                                                   const float* __restrict__ a1,
                                                   const float* __restrict__ a2,
                                                   float* __restrict__ st,
                                                   u16* __restrict__ wE) {
  const int tid = threadIdx.x, c = blockIdx.x;
  float s[8], q[8];
#pragma unroll
  for (int k = 0; k < 8; ++k) { s[k] = 0.f; q[k] = 0.f; }
  for (int i = tid; i < 1024; i += 256) {
#pragma unroll
    for (int k = 0; k < 8; ++k) {
      s[k] += pC[i * 1024 + k * 64 + c];
      q[k] += pC[i * 1024 + 512 + k * 64 + c];
    }
  }
#pragma unroll
  for (int k = 0; k < 8; ++k) {
#pragma unroll
    for (int off = 32; off; off >>= 1) { s[k] += __shfl_xor(s[k], off); q[k] += __shfl_xor(q[k], off); }
  }
  __shared__ float red[4][16];
  __shared__ float gL[8];
  int wv = tid >> 6;
  if ((tid & 63) == 0) {
#pragma unroll
    for (int k = 0; k < 8; ++k) { red[wv][k * 2] = s[k]; red[wv][k * 2 + 1] = q[k]; }
  }
  __syncthreads();
  if (tid == 0) {
    float suf = 0.f, bias = 0.f;
    for (int k = 7; k >= 0; --k) {
      float S = red[0][k * 2] + red[1][k * 2] + red[2][k * 2] + red[3][k * 2];
      float Q = red[0][k * 2 + 1] + red[1][k * 2 + 1] + red[2][k * 2 + 1] + red[3][k * 2 + 1];
      float mu = S * (1.f / NRED);
      float var = Q * (1.f / NRED) - mu * mu;
      float rr = rsqrtf(var + EPS);
      bias -= a2[k] * mu * rr;
      suf += a2[k] * rr;
      gL[k] = suf;
    }
    st[1792 + c] = bias;
    int g = c >> 3;
    float m1 = 0.f, m2 = 0.f;
    for (int i = g; i < 8; ++i) { m1 += a1[i]; m2 += a2[i]; }
    st[8192 + c] = m1 * m2;
  }
  __syncthreads();
  for (int idx = tid; idx < 576; idx += 256) {
    int tap = idx >> 6, ci = idx & 63;
    wE[(tap * 64 + c) * 64 + ci] = f2bf(w2[(c * 64 + ci) * 9 + tap] * gL[ci >> 3]);
  }
}

// ---------------- convE: mixed conv2 + fused epilogue ------------------------
// Same structure as convA. grid (16, 64).
// MODE 0: n1T/n1reluT | 1: n2reluT = relu(v + pool(n1T)*cm) | 2: out = v + x*cm | 3: out += v
template <int MODE>
__global__ __launch_bounds__(256, 2) void convE_k(const u16* __restrict__ t,
                                                  const float* __restrict__ st,
                                                  const u16* __restrict__ wE,
                                                  float* __restrict__ outp,
                                                  const float* __restrict__ xin,
                                                  u16* __restrict__ d1,
                                                  u16* __restrict__ d2) {
  __shared__ __align__(16) u16 shp[136 * 80];
  __shared__ float cmL[64], biasL[64];
  const int tid = threadIdx.x;
  const int b = blockIdx.y, R0 = blockIdx.x * 2;
  if (tid < 64) { cmL[tid] = st[8192 + tid]; biasL[tid] = st[1792 + tid]; }
  stage_patch(t + (size_t)b * IMST + (size_t)R0 * 2176, shp, tid);
  const int lane = tid & 63, w = tid >> 6;
  const int ln = lane & 15, quad = lane >> 4;
  const int lr = w >> 1, mh = w & 1;
  bf16x8 A[9][2][2];
#pragma unroll
  for (int tap = 0; tap < 9; ++tap)
#pragma unroll
    for (int m2 = 0; m2 < 2; ++m2)
#pragma unroll
      for (int h = 0; h < 2; ++h)
        A[tap][m2][h] = *(const bf16x8*)&wE[(size_t)((tap * 64 + (mh * 2 + m2) * 16 + ln) * 64) + h * 32 + quad * 8];
  __syncthreads();
  f32x4 acc[2][2];
#pragma unroll
  for (int m2 = 0; m2 < 2; ++m2)
#pragma unroll
    for (int nf = 0; nf < 2; ++nf) acc[m2][nf] = (f32x4){0.f, 0.f, 0.f, 0.f};
#pragma unroll
  for (int tap = 0; tap < 9; ++tap) {
    const int dy = tap / 3, dx = tap % 3;
    const int pb = ((lr + dy) * 34 + ln + dx) * 80 + quad * 8;
#pragma unroll
    for (int h = 0; h < 2; ++h) {
      bf16x8 b0 = *(const bf16x8*)&shp[pb + h * 32];
      bf16x8 b1 = *(const bf16x8*)&shp[pb + 16 * 80 + h * 32];
      acc[0][0] = MFMA16(A[tap][0][h], b0, acc[0][0]);
      acc[0][1] = MFMA16(A[tap][0][h], b1, acc[0][1]);
      acc[1][0] = MFMA16(A[tap][1][h], b0, acc[1][0]);
      acc[1][1] = MFMA16(A[tap][1][h], b1, acc[1][1]);
    }
  }
  const int R = R0 + lr;
#pragma unroll
  for (int m2 = 0; m2 < 2; ++m2) {
    const int cob = (mh * 2 + m2) * 16 + quad * 4;
#pragma unroll
    for (int nf = 0; nf < 2; ++nf) {
      const int C = nf * 16 + ln;
      const size_t haloPx = (size_t)b * IMST + (size_t)((R + 1) * 34 + C + 1) * 64 + cob;
      float v[4];
#pragma unroll
      for (int r = 0; r < 4; ++r) v[r] = acc[m2][nf][r] + biasL[cob + r];
      if (MODE == 0) {
        uint2 pk, pkr;
        pk.x = pk2(v[0], v[1]); pk.y = pk2(v[2], v[3]);
        pkr.x = pk2(fmaxf(v[0], 0.f), fmaxf(v[1], 0.f));
        pkr.y = pk2(fmaxf(v[2], 0.f), fmaxf(v[3], 0.f));
        *(uint2*)&d1[haloPx] = pk;    // n1T (raw, for pool)
        *(uint2*)&d2[haloPx] = pkr;   // n1reluT (for e2 convA)
      } else if (MODE == 1) {
        float ps[4] = {0.f, 0.f, 0.f, 0.f};
        const size_t pb2 = (size_t)b * IMST + (size_t)(R * 34 + C) * 64 + cob;
#pragma unroll
        for (int dy = 0; dy < 3; ++dy)
#pragma unroll
          for (int dx = 0; dx < 3; ++dx) {
            uint2 u = *(const uint2*)&d2[pb2 + (size_t)(dy * 34 + dx) * 64];  // d2 = n1T
            ps[0] += bf2f((u16)(u.x & 0xffff));
            ps[1] += bf2f((u16)(u.x >> 16));
            ps[2] += bf2f((u16)(u.y & 0xffff));
            ps[3] += bf2f((u16)(u.y >> 16));
          }
        float rows = 3.f - (R == 0 ? 1.f : 0.f) - (R == 31 ? 1.f : 0.f);
        float cols = 3.f - (C == 0 ? 1.f : 0.f) - (C == 31 ? 1.f : 0.f);
        float inv = 1.f / (rows * cols);
        uint2 pkr;
        float t0 = fmaxf(v[0] + ps[0] * inv * cmL[cob], 0.f);
        float t1 = fmaxf(v[1] + ps[1] * inv * cmL[cob + 1], 0.f);
        float t2 = fmaxf(v[2] + ps[2] * inv * cmL[cob + 2], 0.f);
        float t3 = fmaxf(v[3] + ps[3] * inv * cmL[cob + 3], 0.f);
        pkr.x = pk2(t0, t1); pkr.y = pk2(t2, t3);
        *(uint2*)&d1[haloPx] = pkr;   // n2reluT
      } else if (MODE == 2) {
        size_t base = (size_t)b * 65536 + (size_t)cob * 1024 + R * 32 + C;
#pragma unroll
        for (int r = 0; r < 4; ++r)
          outp[base + (size_t)r * 1024] = v[r] + xin[base + (size_t)r * 1024] * cmL[cob + r];
      } else {
        size_t base = (size_t)b * 65536 + (size_t)cob * 1024 + R * 32 + C;
#pragma unroll
        for (int r = 0; r < 4; ++r)
          outp[base + (size_t)r * 1024] += v[r];
      }
    }
  }
}

extern "C" void kernel_launch(void* const* d_in, const int* in_sizes, int n_in,
                              void* d_out, int out_size, void* d_ws, size_t ws_size,
                              hipStream_t stream) {
  const float* x  = (const float*)d_in[0];
  const float* a1 = (const float*)d_in[1];
  const float* a2 = (const float*)d_in[2];
  const float* W1[4] = {(const float*)d_in[3], (const float*)d_in[5],
                        (const float*)d_in[7], (const float*)d_in[9]};
  const float* W2[4] = {(const float*)d_in[4], (const float*)d_in[6],
                        (const float*)d_in[8], (const float*)d_in[10]};
  float* out = (float*)d_out;
  char* ws = (char*)d_ws;
  const size_t HB = (size_t)IMST * 64 * 2;  // 9,469,952 B per halo buffer
  u16* xT  = (u16*)ws;
  u16* t   = (u16*)(ws + HB);
  u16* n1T = (u16*)(ws + 2 * HB);
  u16* n1r = (u16*)(ws + 3 * HB);
  u16* n2r = (u16*)(ws + 4 * HB);
  char* p = ws + 5 * HB;
  float* st  = (float*)p;            p += 8256 * 4;
  u16* wT1   = (u16*)p;              p += 4 * 36864 * 2;
  u16* wG    = (u16*)p;              p += 4 * 49152 * 2;
  u16* wE    = (u16*)p;              p += 36864 * 2;
  float* pA  = (float*)p;            p += 1024 * 128 * 4;
  float* pC  = (float*)p;            // 1024*1024*4

  hipMemsetAsync(ws, 0, 5 * HB, stream);  // zero halos (+interiors, overwritten)
  pack_wT1_k<<<36, 256, 0, stream>>>(W1[0], W1[1], W1[2], W1[3], wT1);
  pack_wG_k<<<dim3(96, 4), 256, 0, stream>>>(W2[0], W2[1], W2[2], W2[3], wG);
  transpose_k<<<1024, 256, 0, stream>>>(x, xT);

  dim3 gAE(16, 64), gC(16, 64, 2);
  const u16* ins[4] = {xT, xT, n1r, n2r};
  for (int e = 0; e < 4; ++e) {
    convA_k<<<gAE, 256, 0, stream>>>(ins[e], wT1 + e * 36864, t, pA);
    reducerA_k<<<64, 256, 0, stream>>>(pA, a1, st);
    renorm_k<<<2048, 256, 0, stream>>>(t, st);
    convC_k<<<gC, 256, 0, stream>>>(t, wG + e * 49152, pC);
    redCprepE_k<<<64, 256, 0, stream>>>(pC, W2[e], a1, a2, st, wE);
    if (e == 0) {
      convE_k<0><<<gAE, 256, 0, stream>>>(t, st, wE, nullptr, nullptr, n1T, n1r);
    } else if (e == 1) {
      convE_k<1><<<gAE, 256, 0, stream>>>(t, st, wE, nullptr, nullptr, n2r, n1T);
    } else if (e == 2) {
      convE_k<2><<<gAE, 256, 0, stream>>>(t, st, wE, out, x, nullptr, nullptr);
    } else {
      convE_k<3><<<gAE, 256, 0, stream>>>(t, st, wE, out, nullptr, nullptr, nullptr);
    }
  }
}

// Round 9
// 501.489 us; speedup vs baseline: 2.2083x; 1.0976x over previous
//
#include <hip/hip_runtime.h>

#define EPS 1e-5f
#define NRED 65536.0f   // B*H*W = 64*32*32
#define IMST 73984      // 34*34*64 halo image stride (elements)
#define PATCH 10880     // 136 px * 80 padded ci

typedef short bf16x8 __attribute__((ext_vector_type(8)));
typedef float f32x4 __attribute__((ext_vector_type(4)));
typedef unsigned short u16;

#define MFMA16(a, b, c) __builtin_amdgcn_mfma_f32_16x16x32_bf16(a, b, c, 0, 0, 0)

__device__ __forceinline__ u16 f2bf(float x) {  // RNE f32->bf16
  union { float f; unsigned u; } v; v.f = x;
  unsigned r = v.u + 0x7FFF + ((v.u >> 16) & 1);
  return (u16)(r >> 16);
}
__device__ __forceinline__ float bf2f(u16 h) {
  union { unsigned u; float f; } v; v.u = ((unsigned)h) << 16;
  return v.f;
}
__device__ __forceinline__ unsigned pk2(float a, float b) {
  return (unsigned)f2bf(a) | ((unsigned)f2bf(b) << 16);
}

// DPP row-shift reduce over 16-lane rows; sum valid in ln==15. Pure VALU.
template <int CTRL>
__device__ __forceinline__ float dpp_mov(float x) {
  int xi = __builtin_bit_cast(int, x);
  int r = __builtin_amdgcn_update_dpp(0, xi, CTRL, 0xF, 0xF, true);
  return __builtin_bit_cast(float, r);
}
__device__ __forceinline__ float row_reduce16(float x) {
  x += dpp_mov<0x111>(x);
  x += dpp_mov<0x112>(x);
  x += dpp_mov<0x114>(x);
  x += dpp_mov<0x118>(x);
  return x;
}

// ---- LDS patch staging (4 rows x 34 cols x 64 ci, pixel stride 80) ----------
// Halo pixels forced to 0 (global halo contents are don't-care -> no memset).
__device__ __forceinline__ void stage_mask(const u16* __restrict__ src,
                                           u16* __restrict__ shp, int tid, int R0) {
#pragma unroll
  for (int i = 0; i < 5; ++i) {
    int c = i * 256 + tid;
    if (i == 4 && tid >= 64) break;
    int px = c >> 3, oct = c & 7;
    int prow = px / 34, pcol = px - prow * 34;
    bool halo = (R0 + prow == 0) || (R0 + prow == 33) || (pcol == 0) || (pcol == 33);
    uint4 v = {0u, 0u, 0u, 0u};
    if (!halo) v = *(const uint4*)&src[(size_t)c * 8];
    *(uint4*)&shp[px * 80 + oct * 8] = v;
  }
}

// Affine staging: h = t*s1[ci]+b1[ci] (interior), 0 (halo) — renorm fused here.
__device__ __forceinline__ void stage_affine(const u16* __restrict__ src,
                                             u16* __restrict__ shp, int tid, int R0,
                                             const float* __restrict__ stE) {
  const int oct = tid & 7;
  float s[8], bb[8];
#pragma unroll
  for (int j = 0; j < 8; ++j) { s[j] = stE[oct * 8 + j]; bb[j] = stE[64 + oct * 8 + j]; }
#pragma unroll
  for (int i = 0; i < 5; ++i) {
    int c = i * 256 + tid;
    if (i == 4 && tid >= 64) break;
    int px = c >> 3;
    int prow = px / 34, pcol = px - prow * 34;
    bool halo = (R0 + prow == 0) || (R0 + prow == 33) || (pcol == 0) || (pcol == 33);
    uint4 o = {0u, 0u, 0u, 0u};
    if (!halo) {
      uint4 u = *(const uint4*)&src[(size_t)c * 8];
      unsigned uv[4] = {u.x, u.y, u.z, u.w};
      unsigned rv[4];
#pragma unroll
      for (int p2 = 0; p2 < 4; ++p2) {
        float lo = bf2f((u16)(uv[p2] & 0xffff)) * s[p2 * 2] + bb[p2 * 2];
        float hi = bf2f((u16)(uv[p2] >> 16)) * s[p2 * 2 + 1] + bb[p2 * 2 + 1];
        rv[p2] = pk2(lo, hi);
      }
      o.x = rv[0]; o.y = rv[1]; o.z = rv[2]; o.w = rv[3];
    }
    *(uint4*)&shp[px * 80 + (c & 7) * 8] = o;
  }
}

// st layout: per edge e at st+e*2048: [0,64) s1 | [64,128) b1 | [128,192) bias2.
// Global: st[8192,8256) = cm.

__global__ void pack_wT1_k(const float* __restrict__ w0, const float* __restrict__ w1,
                           const float* __restrict__ w2, const float* __restrict__ w3,
                           u16* __restrict__ wT1) {
  int e = blockIdx.x / 9, tap = blockIdx.x % 9;
  const float* w = e == 0 ? w0 : e == 1 ? w1 : e == 2 ? w2 : w3;
  u16* dst = wT1 + e * 36864 + tap * 4096;
  for (int idx = threadIdx.x; idx < 4096; idx += 256) {
    int co = idx >> 6, ci = idx & 63;
    dst[idx] = f2bf(w[(co * 64 + ci) * 9 + tap]);
  }
}

__global__ void pack_wG_k(const float* __restrict__ w0, const float* __restrict__ w1,
                          const float* __restrict__ w2, const float* __restrict__ w3,
                          u16* __restrict__ wG) {
  int e = blockIdx.y;
  const float* w = e == 0 ? w0 : e == 1 ? w1 : e == 2 ? w2 : w3;
  int bx = blockIdx.x;              // g*12 + ch*4 + q
  int q = bx & 3, ch = (bx >> 2) % 3, g = bx / 12;
  int tap = ch * 4 + q;
  u16* dst = wG + e * 49152 + bx * 512;
  for (int idx = threadIdx.x; idx < 512; idx += 256) {
    int co = idx >> 3, cig = idx & 7;
    float v = (tap <= 8) ? w[(co * 64 + g * 8 + cig) * 9 + tap] : 0.f;
    dst[idx] = f2bf(v);
  }
}

// x (NCHW f32) -> xT = bf16(relu(x)) halo pixel-major (interior only).
__global__ __launch_bounds__(256) void transpose_k(const float* __restrict__ x,
                                                   u16* __restrict__ xT) {
  __shared__ __align__(16) u16 sh[64 * 72];
  const int tid = threadIdx.x;
  const int b = blockIdx.x >> 4, slab = blockIdx.x & 15;
  const int ln = tid & 63, w = tid >> 6;
  const float* xb = x + (size_t)b * 65536 + slab * 64;
#pragma unroll
  for (int i = 0; i < 16; ++i) {
    int ci = w + i * 4;
    float v = xb[ci * 1024 + ln];
    sh[ln * 72 + ci] = f2bf(fmaxf(v, 0.f));
  }
  __syncthreads();
  u16* dst = xT + (size_t)b * IMST;
#pragma unroll
  for (int j = 0; j < 2; ++j) {
    int idx = tid + j * 256;
    int p = idx >> 3, oct = idx & 7;
    int gp = slab * 64 + p;
    int R = gp >> 5, C = gp & 31;
    *(uint4*)&dst[((R + 1) * 34 + C + 1) * 64 + oct * 8] = *(const uint4*)&sh[p * 72 + oct * 8];
  }
}

// zero halo strips of one halo buffer (needed only for n1T: pool reads global).
__global__ void zero_halo_k(u16* __restrict__ buf) {
  int b = blockIdx.x, tid = threadIdx.x;
  if (tid >= 132) return;
  int R, C;
  if (tid < 34) { R = 0; C = tid; }
  else if (tid < 68) { R = 33; C = tid - 34; }
  else if (tid < 100) { R = tid - 67; C = 0; }
  else { R = tid - 99; C = 33; }
  u16* p = buf + (size_t)b * IMST + (size_t)(R * 34 + C) * 64;
  uint4 z = {0u, 0u, 0u, 0u};
#pragma unroll
  for (int i = 0; i < 8; ++i) *(uint4*)&p[i * 8] = z;
}

// ---------------- convA (2-edge batched): t = conv3x3(xin, W1) + stats -------
// grid (16, 64, 2); block 256 = 4 waves (lr=w>>1 row, mh=w&1 co-half).
__global__ __launch_bounds__(256, 2) void convA_k(const u16* __restrict__ in0,
                                                  const u16* __restrict__ in1,
                                                  const u16* __restrict__ wTa,
                                                  const u16* __restrict__ wTb,
                                                  u16* __restrict__ t0,
                                                  u16* __restrict__ t1,
                                                  float* __restrict__ pA) {
  __shared__ __align__(16) u16 shp[PATCH];
  __shared__ float sA[64], qA[64];
  const int tid = threadIdx.x;
  const int b = blockIdx.y, R0 = blockIdx.x * 2, z = blockIdx.z;
  const u16* xin = z ? in1 : in0;
  const u16* wT = z ? wTb : wTa;
  u16* t = z ? t1 : t0;
  if (tid < 64) { sA[tid] = 0.f; qA[tid] = 0.f; }
  stage_mask(xin + (size_t)b * IMST + (size_t)R0 * 2176, shp, tid, R0);
  const int lane = tid & 63, w = tid >> 6;
  const int ln = lane & 15, quad = lane >> 4;
  const int lr = w >> 1, mh = w & 1;
  bf16x8 A[9][2][2];
#pragma unroll
  for (int tap = 0; tap < 9; ++tap)
#pragma unroll
    for (int m2 = 0; m2 < 2; ++m2)
#pragma unroll
      for (int h = 0; h < 2; ++h)
        A[tap][m2][h] = *(const bf16x8*)&wT[(size_t)((tap * 64 + (mh * 2 + m2) * 16 + ln) * 64) + h * 32 + quad * 8];
  __syncthreads();
  f32x4 acc[2][2];
#pragma unroll
  for (int m2 = 0; m2 < 2; ++m2)
#pragma unroll
    for (int nf = 0; nf < 2; ++nf) acc[m2][nf] = (f32x4){0.f, 0.f, 0.f, 0.f};
#pragma unroll
  for (int tap = 0; tap < 9; ++tap) {
    const int dy = tap / 3, dx = tap % 3;
    const int pb = ((lr + dy) * 34 + ln + dx) * 80 + quad * 8;
#pragma unroll
    for (int h = 0; h < 2; ++h) {
      bf16x8 b0 = *(const bf16x8*)&shp[pb + h * 32];
      bf16x8 b1 = *(const bf16x8*)&shp[pb + 16 * 80 + h * 32];
      acc[0][0] = MFMA16(A[tap][0][h], b0, acc[0][0]);
      acc[0][1] = MFMA16(A[tap][0][h], b1, acc[0][1]);
      acc[1][0] = MFMA16(A[tap][1][h], b0, acc[1][0]);
      acc[1][1] = MFMA16(A[tap][1][h], b1, acc[1][1]);
    }
  }
  const int R = R0 + lr;
#pragma unroll
  for (int m2 = 0; m2 < 2; ++m2) {
    const int cob = (mh * 2 + m2) * 16 + quad * 4;
#pragma unroll
    for (int nf = 0; nf < 2; ++nf) {
      u16* tb = t + (size_t)b * IMST + (size_t)((R + 1) * 34 + nf * 16 + ln + 1) * 64 + cob;
      uint2 pk;
      pk.x = pk2(acc[m2][nf][0], acc[m2][nf][1]);
      pk.y = pk2(acc[m2][nf][2], acc[m2][nf][3]);
      *(uint2*)tb = pk;
    }
#pragma unroll
    for (int r = 0; r < 4; ++r) {
      float v0 = acc[m2][0][r], v1 = acc[m2][1][r];
      float s = row_reduce16(v0) + row_reduce16(v1);
      float q = row_reduce16(v0 * v0) + row_reduce16(v1 * v1);
      if (ln == 15) {
        atomicAdd(&sA[cob + r], s);
        atomicAdd(&qA[cob + r], q);
      }
    }
  }
  __syncthreads();
  const int blk = z * 1024 + blockIdx.y * 16 + blockIdx.x;
  if (tid < 64) pA[blk * 128 + tid] = sA[tid];
  else if (tid < 128) pA[blk * 128 + tid] = qA[tid - 64];
}

// reducerA (batched): grid (64, 2); writes s1/b1 into stBase + z*2048.
__global__ __launch_bounds__(256) void reducerA_k(const float* __restrict__ pA,
                                                  const float* __restrict__ a1,
                                                  float* __restrict__ stBase) {
  const int tid = threadIdx.x, c = blockIdx.x, z = blockIdx.y;
  const float* pAe = pA + (size_t)z * 1024 * 128;
  float s = 0.f, q = 0.f;
  for (int i = tid; i < 1024; i += 256) {
    s += pAe[i * 128 + c];
    q += pAe[i * 128 + 64 + c];
  }
#pragma unroll
  for (int off = 32; off; off >>= 1) { s += __shfl_xor(s, off); q += __shfl_xor(q, off); }
  __shared__ float red[8];
  int wv = tid >> 6;
  if ((tid & 63) == 0) { red[wv] = s; red[4 + wv] = q; }
  __syncthreads();
  if (tid == 0) {
    float S = red[0] + red[1] + red[2] + red[3];
    float Q = red[4] + red[5] + red[6] + red[7];
    int g = c >> 3;
    float m = 0.f;
    for (int i = g; i < 8; ++i) m += a1[i];
    float mu = S * (1.f / NRED);
    float var = Q * (1.f / NRED) - mu * mu;
    float r = rsqrtf(var + EPS);
    float* stE = stBase + z * 2048;
    stE[c] = r * m;
    stE[64 + c] = -mu * r * m;
  }
}

// ---------------- convC (batched): per-group prefix stats of conv2 -----------
// grid (16, 64, 4): z -> edge=z>>1, co-half=z&1. Affine staging (renorm fused).
__global__ __launch_bounds__(256, 2) void convC_k(const u16* __restrict__ t0,
                                                  const u16* __restrict__ t1,
                                                  const u16* __restrict__ wGa,
                                                  const u16* __restrict__ wGb,
                                                  const float* __restrict__ stBase,
                                                  float* __restrict__ pC) {
  __shared__ __align__(16) u16 shp[PATCH];
  __shared__ __align__(16) u16 shA[96 * 32 * 8];
  __shared__ float sC[256], qC[256];
  const int tid = threadIdx.x;
  const int b = blockIdx.y, R0 = blockIdx.x * 2;
  const int edge = blockIdx.z >> 1, ch2 = blockIdx.z & 1;
  const u16* t = edge ? t1 : t0;
  const u16* wG = edge ? wGb : wGa;
  const float* stE = stBase + edge * 2048;
  float* pCe = pC + (size_t)edge * 1048576;
  sC[tid] = 0.f; qC[tid] = 0.f;
  stage_affine(t + (size_t)b * IMST + (size_t)R0 * 2176, shp, tid, R0, stE);
#pragma unroll
  for (int i = 0; i < 12; ++i) {
    int c = i * 256 + tid;
    int bx = c >> 5, lco = c & 31;
    *(uint4*)&shA[c * 8] = *(const uint4*)&wG[(size_t)(bx * 64 + ch2 * 32 + lco) * 8];
  }
  __syncthreads();
  const int lane = tid & 63, w = tid >> 6;
  const int ln = lane & 15, quad = lane >> 4;
  const int lrow = w >> 1, colbase = (w & 1) * 16;
  int pxo[3];
#pragma unroll
  for (int ch = 0; ch < 3; ++ch) {
    int tp = ch * 4 + quad; if (tp > 8) tp = 8;  // A is zero there
    pxo[ch] = ((lrow + tp / 3) * 34 + colbase + ln + tp % 3) * 80;
  }
  f32x4 acc[8][2];
#pragma unroll
  for (int g = 0; g < 8; ++g)
#pragma unroll
    for (int m = 0; m < 2; ++m) acc[g][m] = (f32x4){0.f, 0.f, 0.f, 0.f};
#pragma unroll
  for (int g = 0; g < 8; ++g) {
#pragma unroll
    for (int ch = 0; ch < 3; ++ch) {
      bf16x8 bx = *(const bf16x8*)&shp[pxo[ch] + g * 8];
#pragma unroll
      for (int mtl = 0; mtl < 2; ++mtl) {
        bf16x8 aw = *(const bf16x8*)&shA[((g * 12 + ch * 4 + quad) * 32 + mtl * 16 + ln) * 8];
        acc[g][mtl] = MFMA16(aw, bx, acc[g][mtl]);
      }
    }
  }
  f32x4 P[2];
  P[0] = (f32x4){0.f, 0.f, 0.f, 0.f};
  P[1] = (f32x4){0.f, 0.f, 0.f, 0.f};
#pragma unroll
  for (int k = 0; k < 8; ++k) {
    P[0] += acc[k][0]; P[1] += acc[k][1];
#pragma unroll
    for (int mtl = 0; mtl < 2; ++mtl) {
#pragma unroll
      for (int r = 0; r < 4; ++r) {
        float v = P[mtl][r];
        float s = row_reduce16(v);
        float q = row_reduce16(v * v);
        if (ln == 15) {
          int lco = mtl * 16 + quad * 4 + r;
          atomicAdd(&sC[k * 32 + lco], s);
          atomicAdd(&qC[k * 32 + lco], q);
        }
      }
    }
  }
  __syncthreads();
  const int blk = blockIdx.y * 16 + blockIdx.x;
  const int k = tid >> 5, lco = tid & 31;
  pCe[blk * 1024 + k * 64 + ch2 * 32 + lco] = sC[tid];
  pCe[blk * 1024 + 512 + k * 64 + ch2 * 32 + lco] = qC[tid];
}

// redCprepE (batched): grid (64, 2): c, z(edge). finalizeC + fold g -> wE.
__global__ __launch_bounds__(256) void redCprepE_k(const float* __restrict__ pC,
                                                   const float* __restrict__ w2a,
                                                   const float* __restrict__ w2b,
                                                   const float* __restrict__ a1,
                                                   const float* __restrict__ a2,
                                                   float* __restrict__ stBase,
                                                   u16* __restrict__ wEbase,
                                                   float* __restrict__ cm) {
  const int tid = threadIdx.x, c = blockIdx.x, z = blockIdx.y;
  const float* pCe = pC + (size_t)z * 1048576;
  const float* w2 = z ? w2b : w2a;
  float* stE = stBase + z * 2048;
  u16* wE = wEbase + z * 36864;
  float s[8], q[8];
#pragma unroll
  for (int k = 0; k < 8; ++k) { s[k] = 0.f; q[k] = 0.f; }
  for (int i = tid; i < 1024; i += 256) {
#pragma unroll
    for (int k = 0; k < 8; ++k) {
      s[k] += pCe[i * 1024 + k * 64 + c];
      q[k] += pCe[i * 1024 + 512 + k * 64 + c];
    }
  }
#pragma unroll
  for (int k = 0; k < 8; ++k) {
#pragma unroll
    for (int off = 32; off; off >>= 1) { s[k] += __shfl_xor(s[k], off); q[k] += __shfl_xor(q[k], off); }
  }
  __shared__ float red[4][16];
  __shared__ float gL[8];
  int wv = tid >> 6;
  if ((tid & 63) == 0) {
#pragma unroll
    for (int k = 0; k < 8; ++k) { red[wv][k * 2] = s[k]; red[wv][k * 2 + 1] = q[k]; }
  }
  __syncthreads();
  if (tid == 0) {
    float suf = 0.f, bias = 0.f;
    for (int k = 7; k >= 0; --k) {
      float S = red[0][k * 2] + red[1][k * 2] + red[2][k * 2] + red[3][k * 2];
      float Q = red[0][k * 2 + 1] + red[1][k * 2 + 1] + red[2][k * 2 + 1] + red[3][k * 2 + 1];
      float mu = S * (1.f / NRED);
      float var = Q * (1.f / NRED) - mu * mu;
      float rr = rsqrtf(var + EPS);
      bias -= a2[k] * mu * rr;
      suf += a2[k] * rr;
      gL[k] = suf;
    }
    stE[128 + c] = bias;
    if (z == 0) {
      int g = c >> 3;
      float m1 = 0.f, m2 = 0.f;
      for (int i = g; i < 8; ++i) { m1 += a1[i]; m2 += a2[i]; }
      cm[c] = m1 * m2;
    }
  }
  __syncthreads();
  for (int idx = tid; idx < 576; idx += 256) {
    int tap = idx >> 6, ci = idx & 63;
    wE[(tap * 64 + c) * 64 + ci] = f2bf(w2[(c * 64 + ci) * 9 + tap] * gL[ci >> 3]);
  }
}

// ---------------- convE (modes 0,1): conv2 + epilogue ------------------------
// MODE 0: d1=n1T raw, d2=n1r relu | MODE 1: d1=n2r relu(v+pool(d2=n1T)*cm)
template <int MODE>
__global__ __launch_bounds__(256, 2) void convE_k(const u16* __restrict__ t,
                                                  const float* __restrict__ stE,
                                                  const u16* __restrict__ wEp,
                                                  u16* __restrict__ d1,
                                                  u16* __restrict__ d2,
                                                  const float* __restrict__ cm) {
  __shared__ __align__(16) u16 shp[PATCH];
  __shared__ float cmL[64], biasL[64];
  const int tid = threadIdx.x;
  const int b = blockIdx.y, R0 = blockIdx.x * 2;
  if (tid < 64) { cmL[tid] = cm[tid]; biasL[tid] = stE[128 + tid]; }
  stage_affine(t + (size_t)b * IMST + (size_t)R0 * 2176, shp, tid, R0, stE);
  const int lane = tid & 63, w = tid >> 6;
  const int ln = lane & 15, quad = lane >> 4;
  const int lr = w >> 1, mh = w & 1;
  bf16x8 A[9][2][2];
#pragma unroll
  for (int tap = 0; tap < 9; ++tap)
#pragma unroll
    for (int m2 = 0; m2 < 2; ++m2)
#pragma unroll
      for (int h = 0; h < 2; ++h)
        A[tap][m2][h] = *(const bf16x8*)&wEp[(size_t)((tap * 64 + (mh * 2 + m2) * 16 + ln) * 64) + h * 32 + quad * 8];
  __syncthreads();
  f32x4 acc[2][2];
#pragma unroll
  for (int m2 = 0; m2 < 2; ++m2)
#pragma unroll
    for (int nf = 0; nf < 2; ++nf) acc[m2][nf] = (f32x4){0.f, 0.f, 0.f, 0.f};
#pragma unroll
  for (int tap = 0; tap < 9; ++tap) {
    const int dy = tap / 3, dx = tap % 3;
    const int pb = ((lr + dy) * 34 + ln + dx) * 80 + quad * 8;
#pragma unroll
    for (int h = 0; h < 2; ++h) {
      bf16x8 b0 = *(const bf16x8*)&shp[pb + h * 32];
      bf16x8 b1 = *(const bf16x8*)&shp[pb + 16 * 80 + h * 32];
      acc[0][0] = MFMA16(A[tap][0][h], b0, acc[0][0]);
      acc[0][1] = MFMA16(A[tap][0][h], b1, acc[0][1]);
      acc[1][0] = MFMA16(A[tap][1][h], b0, acc[1][0]);
      acc[1][1] = MFMA16(A[tap][1][h], b1, acc[1][1]);
    }
  }
  const int R = R0 + lr;
#pragma unroll
  for (int m2 = 0; m2 < 2; ++m2) {
    const int cob = (mh * 2 + m2) * 16 + quad * 4;
#pragma unroll
    for (int nf = 0; nf < 2; ++nf) {
      const int C = nf * 16 + ln;
      const size_t haloPx = (size_t)b * IMST + (size_t)((R + 1) * 34 + C + 1) * 64 + cob;
      float v[4];
#pragma unroll
      for (int r = 0; r < 4; ++r) v[r] = acc[m2][nf][r] + biasL[cob + r];
      if (MODE == 0) {
        uint2 pk, pkr;
        pk.x = pk2(v[0], v[1]); pk.y = pk2(v[2], v[3]);
        pkr.x = pk2(fmaxf(v[0], 0.f), fmaxf(v[1], 0.f));
        pkr.y = pk2(fmaxf(v[2], 0.f), fmaxf(v[3], 0.f));
        *(uint2*)&d1[haloPx] = pk;    // n1T (raw, for pool)
        *(uint2*)&d2[haloPx] = pkr;   // n1r (relu, e2 input)
      } else {
        float ps[4] = {0.f, 0.f, 0.f, 0.f};
        const size_t pb2 = (size_t)b * IMST + (size_t)(R * 34 + C) * 64 + cob;
#pragma unroll
        for (int dy = 0; dy < 3; ++dy)
#pragma unroll
          for (int dx = 0; dx < 3; ++dx) {
            uint2 u = *(const uint2*)&d2[pb2 + (size_t)(dy * 34 + dx) * 64];  // n1T
            ps[0] += bf2f((u16)(u.x & 0xffff));
            ps[1] += bf2f((u16)(u.x >> 16));
            ps[2] += bf2f((u16)(u.y & 0xffff));
            ps[3] += bf2f((u16)(u.y >> 16));
          }
        float rows = 3.f - (R == 0 ? 1.f : 0.f) - (R == 31 ? 1.f : 0.f);
        float cols = 3.f - (C == 0 ? 1.f : 0.f) - (C == 31 ? 1.f : 0.f);
        float inv = 1.f / (rows * cols);
        uint2 pkr;
        float t0v = fmaxf(v[0] + ps[0] * inv * cmL[cob], 0.f);
        float t1v = fmaxf(v[1] + ps[1] * inv * cmL[cob + 1], 0.f);
        float t2v = fmaxf(v[2] + ps[2] * inv * cmL[cob + 2], 0.f);
        float t3v = fmaxf(v[3] + ps[3] * inv * cmL[cob + 3], 0.f);
        pkr.x = pk2(t0v, t1v); pkr.y = pk2(t2v, t3v);
        *(uint2*)&d1[haloPx] = pkr;   // n2r
      }
    }
  }
}

// ---------------- convE23: fused final two convs + output --------------------
// out = (conv(t2)+bias2) + (conv(t3)+bias3) + x*cm.  grid (16, 64).
__global__ __launch_bounds__(256, 2) void convE23_k(const u16* __restrict__ t0,
                                                    const u16* __restrict__ t1,
                                                    const float* __restrict__ stBase,
                                                    const u16* __restrict__ wE2,
                                                    const u16* __restrict__ wE3,
                                                    float* __restrict__ outp,
                                                    const float* __restrict__ x,
                                                    const float* __restrict__ cm) {
  __shared__ __align__(16) u16 shp2[2 * PATCH];
  __shared__ float cmL[64], biasL[64];
  const int tid = threadIdx.x;
  const int b = blockIdx.y, R0 = blockIdx.x * 2;
  if (tid < 64) {
    cmL[tid] = cm[tid];
    biasL[tid] = stBase[128 + tid] + stBase[2048 + 128 + tid];
  }
  stage_affine(t0 + (size_t)b * IMST + (size_t)R0 * 2176, shp2, tid, R0, stBase);
  stage_affine(t1 + (size_t)b * IMST + (size_t)R0 * 2176, shp2 + PATCH, tid, R0, stBase + 2048);
  __syncthreads();
  const int lane = tid & 63, w = tid >> 6;
  const int ln = lane & 15, quad = lane >> 4;
  const int lr = w >> 1, mh = w & 1;
  f32x4 acc[2][2];
#pragma unroll
  for (int m2 = 0; m2 < 2; ++m2)
#pragma unroll
    for (int nf = 0; nf < 2; ++nf) acc[m2][nf] = (f32x4){0.f, 0.f, 0.f, 0.f};
#pragma unroll 1
  for (int ei = 0; ei < 2; ++ei) {
    const u16* wEp = ei ? wE3 : wE2;
    const u16* sp = &shp2[ei * PATCH];
    bf16x8 A[9][2][2];
#pragma unroll
    for (int tap = 0; tap < 9; ++tap)
#pragma unroll
      for (int m2 = 0; m2 < 2; ++m2)
#pragma unroll
        for (int h = 0; h < 2; ++h)
          A[tap][m2][h] = *(const bf16x8*)&wEp[(size_t)((tap * 64 + (mh * 2 + m2) * 16 + ln) * 64) + h * 32 + quad * 8];
#pragma unroll
    for (int tap = 0; tap < 9; ++tap) {
      const int dy = tap / 3, dx = tap % 3;
      const int pb = ((lr + dy) * 34 + ln + dx) * 80 + quad * 8;
#pragma unroll
      for (int h = 0; h < 2; ++h) {
        bf16x8 b0 = *(const bf16x8*)&sp[pb + h * 32];
        bf16x8 b1 = *(const bf16x8*)&sp[pb + 16 * 80 + h * 32];
        acc[0][0] = MFMA16(A[tap][0][h], b0, acc[0][0]);
        acc[0][1] = MFMA16(A[tap][0][h], b1, acc[0][1]);
        acc[1][0] = MFMA16(A[tap][1][h], b0, acc[1][0]);
        acc[1][1] = MFMA16(A[tap][1][h], b1, acc[1][1]);
      }
    }
  }
  const int R = R0 + lr;
#pragma unroll
  for (int m2 = 0; m2 < 2; ++m2) {
    const int cob = (mh * 2 + m2) * 16 + quad * 4;
#pragma unroll
    for (int nf = 0; nf < 2; ++nf) {
      const int C = nf * 16 + ln;
      size_t base = (size_t)b * 65536 + (size_t)cob * 1024 + R * 32 + C;
#pragma unroll
      for (int r = 0; r < 4; ++r)
        outp[base + (size_t)r * 1024] =
            acc[m2][nf][r] + biasL[cob + r] + x[base + (size_t)r * 1024] * cmL[cob + r];
    }
  }
}

extern "C" void kernel_launch(void* const* d_in, const int* in_sizes, int n_in,
                              void* d_out, int out_size, void* d_ws, size_t ws_size,
                              hipStream_t stream) {
  const float* x  = (const float*)d_in[0];
  const float* a1 = (const float*)d_in[1];
  const float* a2 = (const float*)d_in[2];
  const float* W1[4] = {(const float*)d_in[3], (const float*)d_in[5],
                        (const float*)d_in[7], (const float*)d_in[9]};
  const float* W2[4] = {(const float*)d_in[4], (const float*)d_in[6],
                        (const float*)d_in[8], (const float*)d_in[10]};
  float* out = (float*)d_out;
  char* ws = (char*)d_ws;
  const size_t HB = (size_t)IMST * 64 * 2;  // 9,469,952 B per halo buffer
  u16* xT  = (u16*)ws;
  u16* t0  = (u16*)(ws + HB);
  u16* t1  = (u16*)(ws + 2 * HB);
  u16* n1T = (u16*)(ws + 3 * HB);
  u16* n1r = (u16*)(ws + 4 * HB);
  u16* n2r = (u16*)(ws + 5 * HB);
  char* p = ws + 6 * HB;
  float* st  = (float*)p;            p += 8256 * 4;
  u16* wT1   = (u16*)p;              p += 4 * 36864 * 2;
  u16* wG    = (u16*)p;              p += 4 * 49152 * 2;
  u16* wE    = (u16*)p;              p += 4 * 36864 * 2;
  float* pA  = (float*)p;            p += 2 * 1024 * 128 * 4;
  float* pC  = (float*)p;            // 2 * 1024*1024*4
  float* cm  = st + 8192;

  pack_wT1_k<<<36, 256, 0, stream>>>(W1[0], W1[1], W1[2], W1[3], wT1);
  pack_wG_k<<<dim3(96, 4), 256, 0, stream>>>(W2[0], W2[1], W2[2], W2[3], wG);
  transpose_k<<<1024, 256, 0, stream>>>(x, xT);
  zero_halo_k<<<64, 160, 0, stream>>>(n1T);

  dim3 gA(16, 64, 2), gC(16, 64, 4), gE(16, 64);
  // batch edges 0+1 (both consume xT)
  convA_k<<<gA, 256, 0, stream>>>(xT, xT, wT1, wT1 + 36864, t0, t1, pA);
  reducerA_k<<<dim3(64, 2), 256, 0, stream>>>(pA, a1, st);
  convC_k<<<gC, 256, 0, stream>>>(t0, t1, wG, wG + 49152, st, pC);
  redCprepE_k<<<dim3(64, 2), 256, 0, stream>>>(pC, W2[0], W2[1], a1, a2, st, wE, cm);
  convE_k<0><<<gE, 256, 0, stream>>>(t0, st, wE, n1T, n1r, cm);
  convE_k<1><<<gE, 256, 0, stream>>>(t1, st + 2048, wE + 36864, n2r, n1T, cm);
  // batch edges 2+3 (consume n1r, n2r)
  convA_k<<<gA, 256, 0, stream>>>(n1r, n2r, wT1 + 2 * 36864, wT1 + 3 * 36864, t0, t1, pA);
  reducerA_k<<<dim3(64, 2), 256, 0, stream>>>(pA, a1, st + 4096);
  convC_k<<<gC, 256, 0, stream>>>(t0, t1, wG + 2 * 49152, wG + 3 * 49152, st + 4096, pC);
  redCprepE_k<<<dim3(64, 2), 256, 0, stream>>>(pC, W2[2], W2[3], a1, a2, st + 4096,
                                               wE + 2 * 36864, cm);
  convE23_k<<<gE, 256, 0, stream>>>(t0, t1, st + 4096, wE + 2 * 36864, wE + 3 * 36864,
                                    out, x, cm);
}

// Round 10
// 465.262 us; speedup vs baseline: 2.3802x; 1.0779x over previous
//
#include <hip/hip_runtime.h>

#define EPS 1e-5f
#define NRED 65536.0f   // B*H*W = 64*32*32
#define IMST 73984      // 34*34*64 halo image stride (elements)
#define PATCH 8704      // 136 px * 64 ci (swizzled, no pad)

typedef short bf16x8 __attribute__((ext_vector_type(8)));
typedef float f32x4 __attribute__((ext_vector_type(4)));
typedef unsigned short u16;

#define MFMA16(a, b, c) __builtin_amdgcn_mfma_f32_16x16x32_bf16(a, b, c, 0, 0, 0)
// XOR-swizzled LDS patch addressing: kills bank conflicts with zero padding.
#define SWZ(px, oct) ((px) * 64 + (((oct) ^ ((px) & 7)) * 8))

__device__ __forceinline__ u16 f2bf(float x) {  // RNE f32->bf16
  union { float f; unsigned u; } v; v.f = x;
  unsigned r = v.u + 0x7FFF + ((v.u >> 16) & 1);
  return (u16)(r >> 16);
}
__device__ __forceinline__ float bf2f(u16 h) {
  union { unsigned u; float f; } v; v.u = ((unsigned)h) << 16;
  return v.f;
}
__device__ __forceinline__ unsigned pk2(float a, float b) {
  return (unsigned)f2bf(a) | ((unsigned)f2bf(b) << 16);
}

// DPP row-shift reduce over 16-lane rows; sum valid in ln==15. Pure VALU.
template <int CTRL>
__device__ __forceinline__ float dpp_mov(float x) {
  int xi = __builtin_bit_cast(int, x);
  int r = __builtin_amdgcn_update_dpp(0, xi, CTRL, 0xF, 0xF, true);
  return __builtin_bit_cast(float, r);
}
__device__ __forceinline__ float row_reduce16(float x) {
  x += dpp_mov<0x111>(x);
  x += dpp_mov<0x112>(x);
  x += dpp_mov<0x114>(x);
  x += dpp_mov<0x118>(x);
  return x;
}

// ---- swizzled patch staging (4 rows x 34 cols x 64 ci) ----------------------
__device__ __forceinline__ void stage_mask(const u16* __restrict__ src,
                                           u16* __restrict__ shp, int tid, int R0) {
#pragma unroll
  for (int i = 0; i < 5; ++i) {
    int c = i * 256 + tid;
    if (i == 4 && tid >= 64) break;
    int px = c >> 3, oct = c & 7;
    int prow = px / 34, pcol = px - prow * 34;
    bool halo = (R0 + prow == 0) || (R0 + prow == 33) || (pcol == 0) || (pcol == 33);
    uint4 v = {0u, 0u, 0u, 0u};
    if (!halo) v = *(const uint4*)&src[(size_t)c * 8];
    *(uint4*)&shp[SWZ(px, oct)] = v;
  }
}

// Affine staging: h = t*s1[ci]+b1[ci] interior, 0 halo (renorm fused).
__device__ __forceinline__ void stage_affine(const u16* __restrict__ src,
                                             u16* __restrict__ shp, int tid, int R0,
                                             const float* __restrict__ stE) {
  const int oct0 = tid & 7;
  float s[8], bb[8];
#pragma unroll
  for (int j = 0; j < 8; ++j) { s[j] = stE[oct0 * 8 + j]; bb[j] = stE[64 + oct0 * 8 + j]; }
#pragma unroll
  for (int i = 0; i < 5; ++i) {
    int c = i * 256 + tid;
    if (i == 4 && tid >= 64) break;
    int px = c >> 3, oct = c & 7;
    int prow = px / 34, pcol = px - prow * 34;
    bool halo = (R0 + prow == 0) || (R0 + prow == 33) || (pcol == 0) || (pcol == 33);
    uint4 o = {0u, 0u, 0u, 0u};
    if (!halo) {
      uint4 u = *(const uint4*)&src[(size_t)c * 8];
      unsigned uv[4] = {u.x, u.y, u.z, u.w};
      unsigned rv[4];
#pragma unroll
      for (int p2 = 0; p2 < 4; ++p2) {
        float lo = bf2f((u16)(uv[p2] & 0xffff)) * s[p2 * 2] + bb[p2 * 2];
        float hi = bf2f((u16)(uv[p2] >> 16)) * s[p2 * 2 + 1] + bb[p2 * 2 + 1];
        rv[p2] = pk2(lo, hi);
      }
      o.x = rv[0]; o.y = rv[1]; o.z = rv[2]; o.w = rv[3];
    }
    *(uint4*)&shp[SWZ(px, oct)] = o;
  }
}

// st layout: per edge e at st+e*2048: [0,64) s1 | [64,128) b1 | [128,192) bias2.

__global__ void pack_wT1_k(const float* __restrict__ w0, const float* __restrict__ w1,
                           const float* __restrict__ w2, const float* __restrict__ w3,
                           u16* __restrict__ wT1) {
  int e = blockIdx.x / 9, tap = blockIdx.x % 9;
  const float* w = e == 0 ? w0 : e == 1 ? w1 : e == 2 ? w2 : w3;
  u16* dst = wT1 + e * 36864 + tap * 4096;
  for (int idx = threadIdx.x; idx < 4096; idx += 256) {
    int co = idx >> 6, ci = idx & 63;
    dst[idx] = f2bf(w[(co * 64 + ci) * 9 + tap]);
  }
}

// wG64[e][g*8+tap(0..7)][co64][cig8] and wT8[e][g][co64][cig8] (tap 8)
__global__ void pack_wG_k(const float* __restrict__ w0, const float* __restrict__ w1,
                          const float* __restrict__ w2, const float* __restrict__ w3,
                          u16* __restrict__ wG64, u16* __restrict__ wT8) {
  int e = blockIdx.y;
  const float* w = e == 0 ? w0 : e == 1 ? w1 : e == 2 ? w2 : w3;
  int bx = blockIdx.x;  // 0..71
  int g, tap;
  u16* dst;
  if (bx < 64) { g = bx >> 3; tap = bx & 7; dst = wG64 + e * 32768 + bx * 512; }
  else         { g = bx - 64; tap = 8;      dst = wT8 + e * 4096 + g * 512; }
  for (int idx = threadIdx.x; idx < 512; idx += 256) {
    int co = idx >> 3, cig = idx & 7;
    dst[idx] = f2bf(w[(co * 64 + g * 8 + cig) * 9 + tap]);
  }
}

// x (NCHW f32) -> xT = bf16(relu(x)) halo pixel-major (interior only).
__global__ __launch_bounds__(256) void transpose_k(const float* __restrict__ x,
                                                   u16* __restrict__ xT) {
  __shared__ __align__(16) u16 sh[64 * 72];
  const int tid = threadIdx.x;
  const int b = blockIdx.x >> 4, slab = blockIdx.x & 15;
  const int ln = tid & 63, w = tid >> 6;
  const float* xb = x + (size_t)b * 65536 + slab * 64;
#pragma unroll
  for (int i = 0; i < 16; ++i) {
    int ci = w + i * 4;
    float v = xb[ci * 1024 + ln];
    sh[ln * 72 + ci] = f2bf(fmaxf(v, 0.f));
  }
  __syncthreads();
  u16* dst = xT + (size_t)b * IMST;
#pragma unroll
  for (int j = 0; j < 2; ++j) {
    int idx = tid + j * 256;
    int p = idx >> 3, oct = idx & 7;
    int gp = slab * 64 + p;
    int R = gp >> 5, C = gp & 31;
    *(uint4*)&dst[((R + 1) * 34 + C + 1) * 64 + oct * 8] = *(const uint4*)&sh[p * 72 + oct * 8];
  }
}

// zero halo strips of n1T (pool reads raw global n1T incl. halo).
__global__ void zero_halo_k(u16* __restrict__ buf) {
  int b = blockIdx.x, tid = threadIdx.x;
  if (tid >= 132) return;
  int R, C;
  if (tid < 34) { R = 0; C = tid; }
  else if (tid < 68) { R = 33; C = tid - 34; }
  else if (tid < 100) { R = tid - 67; C = 0; }
  else { R = tid - 99; C = 33; }
  u16* p = buf + (size_t)b * IMST + (size_t)(R * 34 + C) * 64;
  uint4 z = {0u, 0u, 0u, 0u};
#pragma unroll
  for (int i = 0; i < 8; ++i) *(uint4*)&p[i * 8] = z;
}

// ---------------- convA (2-edge batched): t = conv3x3(xin, W1) + stats -------
__global__ __launch_bounds__(256, 2) void convA_k(const u16* __restrict__ in0,
                                                  const u16* __restrict__ in1,
                                                  const u16* __restrict__ wTa,
                                                  const u16* __restrict__ wTb,
                                                  u16* __restrict__ t0,
                                                  u16* __restrict__ t1,
                                                  float* __restrict__ pA) {
  __shared__ __align__(16) u16 shp[PATCH];
  __shared__ float sA[64], qA[64];
  const int tid = threadIdx.x;
  const int b = blockIdx.y, R0 = blockIdx.x * 2, z = blockIdx.z;
  const u16* xin = z ? in1 : in0;
  const u16* wT = z ? wTb : wTa;
  u16* t = z ? t1 : t0;
  if (tid < 64) { sA[tid] = 0.f; qA[tid] = 0.f; }
  stage_mask(xin + (size_t)b * IMST + (size_t)R0 * 2176, shp, tid, R0);
  const int lane = tid & 63, w = tid >> 6;
  const int ln = lane & 15, quad = lane >> 4;
  const int lr = w >> 1, mh = w & 1;
  bf16x8 A[9][2][2];
#pragma unroll
  for (int tap = 0; tap < 9; ++tap)
#pragma unroll
    for (int m2 = 0; m2 < 2; ++m2)
#pragma unroll
      for (int h = 0; h < 2; ++h)
        A[tap][m2][h] = *(const bf16x8*)&wT[(size_t)((tap * 64 + (mh * 2 + m2) * 16 + ln) * 64) + h * 32 + quad * 8];
  __syncthreads();
  f32x4 acc[2][2];
#pragma unroll
  for (int m2 = 0; m2 < 2; ++m2)
#pragma unroll
    for (int nf = 0; nf < 2; ++nf) acc[m2][nf] = (f32x4){0.f, 0.f, 0.f, 0.f};
#pragma unroll
  for (int tap = 0; tap < 9; ++tap) {
    const int dy = tap / 3, dx = tap % 3;
    const int px0 = (lr + dy) * 34 + ln + dx;
#pragma unroll
    for (int h = 0; h < 2; ++h) {
      const int oct = h * 4 + quad;
      bf16x8 b0 = *(const bf16x8*)&shp[SWZ(px0, oct)];
      bf16x8 b1 = *(const bf16x8*)&shp[SWZ(px0 + 16, oct)];
      acc[0][0] = MFMA16(A[tap][0][h], b0, acc[0][0]);
      acc[0][1] = MFMA16(A[tap][0][h], b1, acc[0][1]);
      acc[1][0] = MFMA16(A[tap][1][h], b0, acc[1][0]);
      acc[1][1] = MFMA16(A[tap][1][h], b1, acc[1][1]);
    }
  }
  const int R = R0 + lr;
#pragma unroll
  for (int m2 = 0; m2 < 2; ++m2) {
    const int cob = (mh * 2 + m2) * 16 + quad * 4;
#pragma unroll
    for (int nf = 0; nf < 2; ++nf) {
      u16* tb = t + (size_t)b * IMST + (size_t)((R + 1) * 34 + nf * 16 + ln + 1) * 64 + cob;
      uint2 pk;
      pk.x = pk2(acc[m2][nf][0], acc[m2][nf][1]);
      pk.y = pk2(acc[m2][nf][2], acc[m2][nf][3]);
      *(uint2*)tb = pk;
    }
#pragma unroll
    for (int r = 0; r < 4; ++r) {
      float v0 = acc[m2][0][r], v1 = acc[m2][1][r];
      float s = row_reduce16(v0) + row_reduce16(v1);
      float q = row_reduce16(v0 * v0) + row_reduce16(v1 * v1);
      if (ln == 15) {
        atomicAdd(&sA[cob + r], s);
        atomicAdd(&qA[cob + r], q);
      }
    }
  }
  __syncthreads();
  const int blk = z * 1024 + blockIdx.y * 16 + blockIdx.x;
  if (tid < 64) pA[blk * 128 + tid] = sA[tid];
  else if (tid < 128) pA[blk * 128 + tid] = qA[tid - 64];
}

// reducerA (batched): grid (64, 2); writes s1/b1 into stBase + z*2048.
__global__ __launch_bounds__(256) void reducerA_k(const float* __restrict__ pA,
                                                  const float* __restrict__ a1,
                                                  float* __restrict__ stBase) {
  const int tid = threadIdx.x, c = blockIdx.x, z = blockIdx.y;
  const float* pAe = pA + (size_t)z * 1024 * 128;
  float s = 0.f, q = 0.f;
  for (int i = tid; i < 1024; i += 256) {
    s += pAe[i * 128 + c];
    q += pAe[i * 128 + 64 + c];
  }
#pragma unroll
  for (int off = 32; off; off >>= 1) { s += __shfl_xor(s, off); q += __shfl_xor(q, off); }
  __shared__ float red[8];
  int wv = tid >> 6;
  if ((tid & 63) == 0) { red[wv] = s; red[4 + wv] = q; }
  __syncthreads();
  if (tid == 0) {
    float S = red[0] + red[1] + red[2] + red[3];
    float Q = red[4] + red[5] + red[6] + red[7];
    int g = c >> 3;
    float m = 0.f;
    for (int i = g; i < 8; ++i) m += a1[i];
    float mu = S * (1.f / NRED);
    float var = Q * (1.f / NRED) - mu * mu;
    float r = rsqrtf(var + EPS);
    float* stE = stBase + z * 2048;
    stE[c] = r * m;
    stE[64 + c] = -mu * r * m;
  }
}

// ---------------- convC: per-group prefix stats, co-quarter blocks -----------
// grid (16, 64, 8): z -> edge = z>>2, coq = z&3. Block = 2 rows x 32 cols x 16 co,
// 4 waves (lrow x colhalf). LDS 36.9 KB -> 4 blocks/CU. Taps 0-7 from shA,
// tap 8 via quad0-masked shA2 frag.
__global__ __launch_bounds__(256, 4) void convC_k(const u16* __restrict__ t0,
                                                  const u16* __restrict__ t1,
                                                  const u16* __restrict__ wG64,
                                                  const u16* __restrict__ wT8,
                                                  const float* __restrict__ stBase,
                                                  float* __restrict__ pC) {
  __shared__ __align__(16) u16 shp[PATCH];        // 17408 B
  __shared__ __align__(16) u16 shA[64 * 16 * 8];  // 16384 B
  __shared__ __align__(16) u16 shA2[8 * 16 * 8];  // 2048 B
  __shared__ float sC[128], qC[128];              // 1024 B
  const int tid = threadIdx.x;
  const int b = blockIdx.y, R0 = blockIdx.x * 2;
  const int edge = blockIdx.z >> 2, coq = blockIdx.z & 3;
  const u16* t = edge ? t1 : t0;
  const float* stE = stBase + edge * 2048;
  const u16* wGe = wG64 + edge * 32768;
  const u16* wT8e = wT8 + edge * 4096;
  if (tid < 128) { sC[tid] = 0.f; qC[tid] = 0.f; }
  stage_affine(t + (size_t)b * IMST + (size_t)R0 * 2176, shp, tid, R0, stE);
  // stage shA: 1024 chunks [row64][co16][cig8]
#pragma unroll
  for (int i = 0; i < 4; ++i) {
    int c = i * 256 + tid;
    int row = c >> 4, col = c & 15;
    *(uint4*)&shA[c * 8] = *(const uint4*)&wGe[(size_t)(row * 64 + coq * 16 + col) * 8];
  }
  if (tid < 128) {  // shA2: 128 chunks [g8][co16][cig8]
    int g = tid >> 4, col = tid & 15;
    *(uint4*)&shA2[tid * 8] = *(const uint4*)&wT8e[(size_t)(g * 64 + coq * 16 + col) * 8];
  }
  __syncthreads();
  const int lane = tid & 63, w = tid >> 6;
  const int ln = lane & 15, quad = lane >> 4;
  const int lrow = w >> 1, colbase = (w & 1) * 16;
  int px[3];
#pragma unroll
  for (int ch = 0; ch < 3; ++ch) {
    int tp = ch * 4 + quad; if (tp > 8) tp = 8;
    px[ch] = (lrow + tp / 3) * 34 + colbase + ln + tp % 3;
  }
  f32x4 acc[8];
#pragma unroll
  for (int g = 0; g < 8; ++g) acc[g] = (f32x4){0.f, 0.f, 0.f, 0.f};
#pragma unroll
  for (int g = 0; g < 8; ++g) {
#pragma unroll
    for (int ch = 0; ch < 3; ++ch) {
      bf16x8 bx = *(const bf16x8*)&shp[SWZ(px[ch], g)];
      bf16x8 aw;
      if (ch < 2) {
        aw = *(const bf16x8*)&shA[((g * 8 + ch * 4 + quad) * 16 + ln) * 8];
      } else {
        aw = (bf16x8){0, 0, 0, 0, 0, 0, 0, 0};
        if (quad == 0) aw = *(const bf16x8*)&shA2[(g * 16 + ln) * 8];
      }
      acc[g] = MFMA16(aw, bx, acc[g]);
    }
  }
  f32x4 P = (f32x4){0.f, 0.f, 0.f, 0.f};
#pragma unroll
  for (int k = 0; k < 8; ++k) {
    P += acc[k];
#pragma unroll
    for (int r = 0; r < 4; ++r) {
      float v = P[r];
      float s = row_reduce16(v);
      float q = row_reduce16(v * v);
      if (ln == 15) {
        atomicAdd(&sC[k * 16 + quad * 4 + r], s);
        atomicAdd(&qC[k * 16 + quad * 4 + r], q);
      }
    }
  }
  __syncthreads();
  const int blk = blockIdx.y * 16 + blockIdx.x;
  const size_t base = ((size_t)(edge * 4 + coq) * 1024 + blk) * 256;
  if (tid < 128) pC[base + tid] = sC[tid];
  else if (tid < 256) pC[base + 128 + (tid - 128)] = qC[tid - 128];
}

// redCprepE (batched): grid (64, 2): c, z(edge). finalizeC + fold g -> wE.
__global__ __launch_bounds__(256) void redCprepE_k(const float* __restrict__ pC,
                                                   const float* __restrict__ w2a,
                                                   const float* __restrict__ w2b,
                                                   const float* __restrict__ a1,
                                                   const float* __restrict__ a2,
                                                   float* __restrict__ stBase,
                                                   u16* __restrict__ wEbase,
                                                   float* __restrict__ cm) {
  const int tid = threadIdx.x, c = blockIdx.x, z = blockIdx.y;
  const int coq = c >> 4, cl = c & 15;
  const float* w2 = z ? w2b : w2a;
  float* stE = stBase + z * 2048;
  u16* wE = wEbase + z * 36864;
  float s[8], q[8];
#pragma unroll
  for (int k = 0; k < 8; ++k) { s[k] = 0.f; q[k] = 0.f; }
  for (int i = tid; i < 1024; i += 256) {
    const float* pb = pC + ((size_t)(z * 4 + coq) * 1024 + i) * 256;
#pragma unroll
    for (int k = 0; k < 8; ++k) {
      s[k] += pb[k * 16 + cl];
      q[k] += pb[128 + k * 16 + cl];
    }
  }
#pragma unroll
  for (int k = 0; k < 8; ++k) {
#pragma unroll
    for (int off = 32; off; off >>= 1) { s[k] += __shfl_xor(s[k], off); q[k] += __shfl_xor(q[k], off); }
  }
  __shared__ float red[4][16];
  __shared__ float gL[8];
  int wv = tid >> 6;
  if ((tid & 63) == 0) {
#pragma unroll
    for (int k = 0; k < 8; ++k) { red[wv][k * 2] = s[k]; red[wv][k * 2 + 1] = q[k]; }
  }
  __syncthreads();
  if (tid == 0) {
    float suf = 0.f, bias = 0.f;
    for (int k = 7; k >= 0; --k) {
      float S = red[0][k * 2] + red[1][k * 2] + red[2][k * 2] + red[3][k * 2];
      float Q = red[0][k * 2 + 1] + red[1][k * 2 + 1] + red[2][k * 2 + 1] + red[3][k * 2 + 1];
      float mu = S * (1.f / NRED);
      float var = Q * (1.f / NRED) - mu * mu;
      float rr = rsqrtf(var + EPS);
      bias -= a2[k] * mu * rr;
      suf += a2[k] * rr;
      gL[k] = suf;
    }
    stE[128 + c] = bias;
    if (z == 0) {
      int g = c >> 3;
      float m1 = 0.f, m2 = 0.f;
      for (int i = g; i < 8; ++i) { m1 += a1[i]; m2 += a2[i]; }
      cm[c] = m1 * m2;
    }
  }
  __syncthreads();
  for (int idx = tid; idx < 576; idx += 256) {
    int tap = idx >> 6, ci = idx & 63;
    wE[(tap * 64 + c) * 64 + ci] = f2bf(w2[(c * 64 + ci) * 9 + tap] * gL[ci >> 3]);
  }
}

// ---------------- convE (modes 0,1): conv2 + epilogue ------------------------
template <int MODE>
__global__ __launch_bounds__(256, 2) void convE_k(const u16* __restrict__ t,
                                                  const float* __restrict__ stE,
                                                  const u16* __restrict__ wEp,
                                                  u16* __restrict__ d1,
                                                  u16* __restrict__ d2,
                                                  const float* __restrict__ cm) {
  __shared__ __align__(16) u16 shp[PATCH];
  __shared__ float cmL[64], biasL[64];
  const int tid = threadIdx.x;
  const int b = blockIdx.y, R0 = blockIdx.x * 2;
  if (tid < 64) { cmL[tid] = cm[tid]; biasL[tid] = stE[128 + tid]; }
  stage_affine(t + (size_t)b * IMST + (size_t)R0 * 2176, shp, tid, R0, stE);
  const int lane = tid & 63, w = tid >> 6;
  const int ln = lane & 15, quad = lane >> 4;
  const int lr = w >> 1, mh = w & 1;
  bf16x8 A[9][2][2];
#pragma unroll
  for (int tap = 0; tap < 9; ++tap)
#pragma unroll
    for (int m2 = 0; m2 < 2; ++m2)
#pragma unroll
      for (int h = 0; h < 2; ++h)
        A[tap][m2][h] = *(const bf16x8*)&wEp[(size_t)((tap * 64 + (mh * 2 + m2) * 16 + ln) * 64) + h * 32 + quad * 8];
  __syncthreads();
  f32x4 acc[2][2];
#pragma unroll
  for (int m2 = 0; m2 < 2; ++m2)
#pragma unroll
    for (int nf = 0; nf < 2; ++nf) acc[m2][nf] = (f32x4){0.f, 0.f, 0.f, 0.f};
#pragma unroll
  for (int tap = 0; tap < 9; ++tap) {
    const int dy = tap / 3, dx = tap % 3;
    const int px0 = (lr + dy) * 34 + ln + dx;
#pragma unroll
    for (int h = 0; h < 2; ++h) {
      const int oct = h * 4 + quad;
      bf16x8 b0 = *(const bf16x8*)&shp[SWZ(px0, oct)];
      bf16x8 b1 = *(const bf16x8*)&shp[SWZ(px0 + 16, oct)];
      acc[0][0] = MFMA16(A[tap][0][h], b0, acc[0][0]);
      acc[0][1] = MFMA16(A[tap][0][h], b1, acc[0][1]);
      acc[1][0] = MFMA16(A[tap][1][h], b0, acc[1][0]);
      acc[1][1] = MFMA16(A[tap][1][h], b1, acc[1][1]);
    }
  }
  const int R = R0 + lr;
#pragma unroll
  for (int m2 = 0; m2 < 2; ++m2) {
    const int cob = (mh * 2 + m2) * 16 + quad * 4;
#pragma unroll
    for (int nf = 0; nf < 2; ++nf) {
      const int C = nf * 16 + ln;
      const size_t haloPx = (size_t)b * IMST + (size_t)((R + 1) * 34 + C + 1) * 64 + cob;
      float v[4];
#pragma unroll
      for (int r = 0; r < 4; ++r) v[r] = acc[m2][nf][r] + biasL[cob + r];
      if (MODE == 0) {
        uint2 pk, pkr;
        pk.x = pk2(v[0], v[1]); pk.y = pk2(v[2], v[3]);
        pkr.x = pk2(fmaxf(v[0], 0.f), fmaxf(v[1], 0.f));
        pkr.y = pk2(fmaxf(v[2], 0.f), fmaxf(v[3], 0.f));
        *(uint2*)&d1[haloPx] = pk;    // n1T (raw, for pool)
        *(uint2*)&d2[haloPx] = pkr;   // n1r (relu, e2 input)
      } else {
        float ps[4] = {0.f, 0.f, 0.f, 0.f};
        const size_t pb2 = (size_t)b * IMST + (size_t)(R * 34 + C) * 64 + cob;
#pragma unroll
        for (int dy = 0; dy < 3; ++dy)
#pragma unroll
          for (int dx = 0; dx < 3; ++dx) {
            uint2 u = *(const uint2*)&d2[pb2 + (size_t)(dy * 34 + dx) * 64];  // n1T
            ps[0] += bf2f((u16)(u.x & 0xffff));
            ps[1] += bf2f((u16)(u.x >> 16));
            ps[2] += bf2f((u16)(u.y & 0xffff));
            ps[3] += bf2f((u16)(u.y >> 16));
          }
        float rows = 3.f - (R == 0 ? 1.f : 0.f) - (R == 31 ? 1.f : 0.f);
        float cols = 3.f - (C == 0 ? 1.f : 0.f) - (C == 31 ? 1.f : 0.f);
        float inv = 1.f / (rows * cols);
        uint2 pkr;
        float t0v = fmaxf(v[0] + ps[0] * inv * cmL[cob], 0.f);
        float t1v = fmaxf(v[1] + ps[1] * inv * cmL[cob + 1], 0.f);
        float t2v = fmaxf(v[2] + ps[2] * inv * cmL[cob + 2], 0.f);
        float t3v = fmaxf(v[3] + ps[3] * inv * cmL[cob + 3], 0.f);
        pkr.x = pk2(t0v, t1v); pkr.y = pk2(t2v, t3v);
        *(uint2*)&d1[haloPx] = pkr;   // n2r
      }
    }
  }
}

// ---------------- convE23: fused final two convs + output --------------------
__global__ __launch_bounds__(256, 2) void convE23_k(const u16* __restrict__ t0,
                                                    const u16* __restrict__ t1,
                                                    const float* __restrict__ stBase,
                                                    const u16* __restrict__ wE2,
                                                    const u16* __restrict__ wE3,
                                                    float* __restrict__ outp,
                                                    const float* __restrict__ x,
                                                    const float* __restrict__ cm) {
  __shared__ __align__(16) u16 shp2[2 * PATCH];
  __shared__ float cmL[64], biasL[64];
  const int tid = threadIdx.x;
  const int b = blockIdx.y, R0 = blockIdx.x * 2;
  if (tid < 64) {
    cmL[tid] = cm[tid];
    biasL[tid] = stBase[128 + tid] + stBase[2048 + 128 + tid];
  }
  stage_affine(t0 + (size_t)b * IMST + (size_t)R0 * 2176, shp2, tid, R0, stBase);
  stage_affine(t1 + (size_t)b * IMST + (size_t)R0 * 2176, shp2 + PATCH, tid, R0, stBase + 2048);
  __syncthreads();
  const int lane = tid & 63, w = tid >> 6;
  const int ln = lane & 15, quad = lane >> 4;
  const int lr = w >> 1, mh = w & 1;
  f32x4 acc[2][2];
#pragma unroll
  for (int m2 = 0; m2 < 2; ++m2)
#pragma unroll
    for (int nf = 0; nf < 2; ++nf) acc[m2][nf] = (f32x4){0.f, 0.f, 0.f, 0.f};
#pragma unroll 1
  for (int ei = 0; ei < 2; ++ei) {
    const u16* wEp = ei ? wE3 : wE2;
    const u16* sp = &shp2[ei * PATCH];
    bf16x8 A[9][2][2];
#pragma unroll
    for (int tap = 0; tap < 9; ++tap)
#pragma unroll
      for (int m2 = 0; m2 < 2; ++m2)
#pragma unroll
        for (int h = 0; h < 2; ++h)
          A[tap][m2][h] = *(const bf16x8*)&wEp[(size_t)((tap * 64 + (mh * 2 + m2) * 16 + ln) * 64) + h * 32 + quad * 8];
#pragma unroll
    for (int tap = 0; tap < 9; ++tap) {
      const int dy = tap / 3, dx = tap % 3;
      const int px0 = (lr + dy) * 34 + ln + dx;
#pragma unroll
      for (int h = 0; h < 2; ++h) {
        const int oct = h * 4 + quad;
        bf16x8 b0 = *(const bf16x8*)&sp[SWZ(px0, oct)];
        bf16x8 b1 = *(const bf16x8*)&sp[SWZ(px0 + 16, oct)];
        acc[0][0] = MFMA16(A[tap][0][h], b0, acc[0][0]);
        acc[0][1] = MFMA16(A[tap][0][h], b1, acc[0][1]);
        acc[1][0] = MFMA16(A[tap][1][h], b0, acc[1][0]);
        acc[1][1] = MFMA16(A[tap][1][h], b1, acc[1][1]);
      }
    }
  }
  const int R = R0 + lr;
#pragma unroll
  for (int m2 = 0; m2 < 2; ++m2) {
    const int cob = (mh * 2 + m2) * 16 + quad * 4;
#pragma unroll
    for (int nf = 0; nf < 2; ++nf) {
      const int C = nf * 16 + ln;
      size_t base = (size_t)b * 65536 + (size_t)cob * 1024 + R * 32 + C;
#pragma unroll
      for (int r = 0; r < 4; ++r)
        outp[base + (size_t)r * 1024] =
            acc[m2][nf][r] + biasL[cob + r] + x[base + (size_t)r * 1024] * cmL[cob + r];
    }
  }
}

extern "C" void kernel_launch(void* const* d_in, const int* in_sizes, int n_in,
                              void* d_out, int out_size, void* d_ws, size_t ws_size,
                              hipStream_t stream) {
  const float* x  = (const float*)d_in[0];
  const float* a1 = (const float*)d_in[1];
  const float* a2 = (const float*)d_in[2];
  const float* W1[4] = {(const float*)d_in[3], (const float*)d_in[5],
                        (const float*)d_in[7], (const float*)d_in[9]};
  const float* W2[4] = {(const float*)d_in[4], (const float*)d_in[6],
                        (const float*)d_in[8], (const float*)d_in[10]};
  float* out = (float*)d_out;
  char* ws = (char*)d_ws;
  const size_t HB = (size_t)IMST * 64 * 2;  // 9,469,952 B per halo buffer
  u16* xT  = (u16*)ws;
  u16* t0  = (u16*)(ws + HB);
  u16* t1  = (u16*)(ws + 2 * HB);
  u16* n1T = (u16*)(ws + 3 * HB);
  u16* n1r = (u16*)(ws + 4 * HB);
  u16* n2r = (u16*)(ws + 5 * HB);
  char* p = ws + 6 * HB;
  float* st  = (float*)p;            p += 8256 * 4;
  u16* wT1   = (u16*)p;              p += 4 * 36864 * 2;
  u16* wG64  = (u16*)p;              p += 4 * 32768 * 2;
  u16* wT8   = (u16*)p;              p += 4 * 4096 * 2;
  u16* wE    = (u16*)p;              p += 4 * 36864 * 2;
  float* pA  = (float*)p;            p += 2 * 1024 * 128 * 4;
  float* pC  = (float*)p;            // 8 * 1024 * 256 * 4 = 8 MB
  float* cm  = st + 8192;

  pack_wT1_k<<<36, 256, 0, stream>>>(W1[0], W1[1], W1[2], W1[3], wT1);
  pack_wG_k<<<dim3(72, 4), 256, 0, stream>>>(W2[0], W2[1], W2[2], W2[3], wG64, wT8);
  transpose_k<<<1024, 256, 0, stream>>>(x, xT);
  zero_halo_k<<<64, 160, 0, stream>>>(n1T);

  dim3 gA(16, 64, 2), gC(16, 64, 8), gE(16, 64);
  // batch edges 0+1 (both consume xT)
  convA_k<<<gA, 256, 0, stream>>>(xT, xT, wT1, wT1 + 36864, t0, t1, pA);
  reducerA_k<<<dim3(64, 2), 256, 0, stream>>>(pA, a1, st);
  convC_k<<<gC, 256, 0, stream>>>(t0, t1, wG64, wT8, st, pC);
  redCprepE_k<<<dim3(64, 2), 256, 0, stream>>>(pC, W2[0], W2[1], a1, a2, st, wE, cm);
  convE_k<0><<<gE, 256, 0, stream>>>(t0, st, wE, n1T, n1r, cm);
  convE_k<1><<<gE, 256, 0, stream>>>(t1, st + 2048, wE + 36864, n2r, n1T, cm);
  // batch edges 2+3 (consume n1r, n2r)
  convA_k<<<gA, 256, 0, stream>>>(n1r, n2r, wT1 + 2 * 36864, wT1 + 3 * 36864, t0, t1, pA);
  reducerA_k<<<dim3(64, 2), 256, 0, stream>>>(pA, a1, st + 4096);
  convC_k<<<gC, 256, 0, stream>>>(t0, t1, wG64 + 2 * 32768, wT8 + 2 * 4096, st + 4096, pC);
  redCprepE_k<<<dim3(64, 2), 256, 0, stream>>>(pC, W2[2], W2[3], a1, a2, st + 4096,
                                               wE + 2 * 36864, cm);
  convE23_k<<<gE, 256, 0, stream>>>(t0, t1, st + 4096, wE + 2 * 36864, wE + 3 * 36864,
                                    out, x, cm);
}